// Round 1
// baseline (3869.957 us; speedup 1.0000x reference)
//
#include <hip/hip_runtime.h>
#include <hip/hip_bf16.h>
#include <stdint.h>

namespace {

constexpr int Z0 = 41, Y0 = 256, X0 = 256;     // level 1 & 5 dims
constexpr int Z2 = 21, Y2 = 128, X2 = 128;     // level 2 dims
constexpr int Z3 = 11, Y3 = 64,  X3 = 64;      // level 3 dims
constexpr int Z4 = 21, Y4 = 127, X4 = 127;     // level 4 dims
constexpr int NZYX0 = Z0 * Y0 * X0;            // 2,686,976
constexpr int NZYX2 = Z2 * Y2 * X2;            // 344,064
constexpr int NZYX3 = Z3 * Y3 * X3;            // 45,056
constexpr int NZYX4 = Z4 * Y4 * X4;            // 338,709

using bf16 = __hip_bfloat16;

__global__ __launch_bounds__(256) void sentinel_k(float* out) { out[0] = 12345.0f; }

__global__ __launch_bounds__(256) void scatter_k(const float* __restrict__ feats,
                                                 const int* __restrict__ coords,
                                                 bf16* __restrict__ dense,
                                                 uint8_t* __restrict__ m0, int n) {
    int v = blockIdx.x * 256 + threadIdx.x;
    if (v >= n) return;
    int z = coords[v * 4 + 1], y = coords[v * 4 + 2], x = coords[v * 4 + 3];
    int p = (z * Y0 + y) * X0 + x;
    m0[p] = 1;
#pragma unroll
    for (int c = 0; c < 4; ++c)
        dense[c * NZYX0 + p] = __float2bfloat16(feats[v * 4 + c]);
}

// conv weight (COUT, CIN, 3,3,3) -> wT[(ci*27+tap)*COUT + co]
__global__ __launch_bounds__(256) void repack_conv_k(const float* __restrict__ w,
                                                     float* __restrict__ wT, int CIN, int COUT) {
    int i = blockIdx.x * 256 + threadIdx.x;
    int n = CIN * COUT * 27;
    if (i >= n) return;
    int co = i / (CIN * 27);
    int r = i - co * CIN * 27;
    int ci = r / 27;
    int tap = r - ci * 27;
    wT[(ci * 27 + tap) * COUT + co] = w[(co * CIN + ci) * 27 + tap];
}

// tconv weight stored (CIN, COUT, 3,3,3) -> wT[(ci*27+tap)*COUT + co]
__global__ __launch_bounds__(256) void repack_tconv_k(const float* __restrict__ w,
                                                      float* __restrict__ wT, int CIN, int COUT) {
    int i = blockIdx.x * 256 + threadIdx.x;
    int n = CIN * COUT * 27;
    if (i >= n) return;
    int ci = i / (COUT * 27);
    int r = i - ci * COUT * 27;
    int co = r / 27;
    int tap = r - co * 27;
    wT[(ci * 27 + tap) * COUT + co] = w[(ci * COUT + co) * 27 + tap];
}

// mask dilation: out[o] = OR_{d in 3^3} in[o*stride + d - 1]
__global__ __launch_bounds__(256) void dilate_k(const uint8_t* __restrict__ in,
                                                uint8_t* __restrict__ out,
                                                int Zi, int Yi, int Xi,
                                                int Zo, int Yo, int Xo, int stride) {
    int idx = blockIdx.x * 256 + threadIdx.x;
    int total = Zo * Yo * Xo;
    if (idx >= total) return;
    int x = idx % Xo;
    int t = idx / Xo;
    int y = t % Yo;
    int z = t / Yo;
    int YX = Yi * Xi;
    uint8_t r = 0;
    for (int kz = 0; kz < 3; ++kz) {
        int zi = z * stride + kz - 1;
        if ((unsigned)zi >= (unsigned)Zi) continue;
        for (int ky = 0; ky < 3; ++ky) {
            int yi = y * stride + ky - 1;
            if ((unsigned)yi >= (unsigned)Yi) continue;
            for (int kx = 0; kx < 3; ++kx) {
                int xi = x * stride + kx - 1;
                if ((unsigned)xi >= (unsigned)Xi) continue;
                r |= in[zi * YX + yi * Xi + xi];
            }
        }
    }
    out[idx] = r ? 1 : 0;
}

// transposed (stride-2) mask dilation: out[o] = OR over taps j with (o+1-j) even,
// i=(o+1-j)/2 in range, of in[i]
__global__ __launch_bounds__(256) void tdilate_k(const uint8_t* __restrict__ in,
                                                 uint8_t* __restrict__ out,
                                                 int Zi, int Yi, int Xi,
                                                 int Zo, int Yo, int Xo) {
    int idx = blockIdx.x * 256 + threadIdx.x;
    int total = Zo * Yo * Xo;
    if (idx >= total) return;
    int x = idx % Xo;
    int t = idx / Xo;
    int y = t % Yo;
    int z = t / Yo;
    int YX = Yi * Xi;
    uint8_t r = 0;
    for (int kz = 0; kz < 3; ++kz) {
        int tz = z + 1 - kz;
        if (tz & 1) continue;
        int zi = tz >> 1;
        if ((unsigned)zi >= (unsigned)Zi) continue;
        for (int ky = 0; ky < 3; ++ky) {
            int ty = y + 1 - ky;
            if (ty & 1) continue;
            int yi = ty >> 1;
            if ((unsigned)yi >= (unsigned)Yi) continue;
            for (int kx = 0; kx < 3; ++kx) {
                int tx = x + 1 - kx;
                if (tx & 1) continue;
                int xi = tx >> 1;
                if ((unsigned)xi >= (unsigned)Xi) continue;
                r |= in[zi * YX + yi * Xi + xi];
            }
        }
    }
    out[idx] = r ? 1 : 0;
}

// direct 3x3x3 conv, pad 1, stride STRIDE; fused bn(scale,shift)+relu+mask.
// input layout [ci][z][y][x] bf16, output [co][z][y][x] (bf16, or f32 if FINAL)
template <int CIN, int COUT, int STRIDE, bool FINAL>
__global__ __launch_bounds__(256) void conv3_k(
    const bf16* __restrict__ in, const float* __restrict__ wT,
    const float* __restrict__ scale, const float* __restrict__ shift,
    const uint8_t* __restrict__ mask, void* __restrict__ outv,
    int Zi, int Yi, int Xi, int Zo, int Yo, int Xo) {
    const int total = Zo * Yo * Xo;
    const int idx = blockIdx.x * 256 + threadIdx.x;
    if (idx >= total) return;
    const int x = idx % Xo;
    const int t = idx / Xo;
    const int y = t % Yo;
    const int z = t / Yo;
    const uint8_t mk = mask[idx];

    bf16* outb = (bf16*)outv;
    float* outf = (float*)outv;

    if (__ballot(mk != 0) == 0ull) {  // whole wave masked out -> write zeros
#pragma unroll
        for (int co = 0; co < COUT; ++co) {
            if constexpr (FINAL) outf[co * total + idx] = 0.f;
            else outb[co * total + idx] = __float2bfloat16(0.f);
        }
        return;
    }

    float acc[COUT];
#pragma unroll
    for (int co = 0; co < COUT; ++co) acc[co] = 0.f;

    const int YX = Yi * Xi;
    const int ZYX = Zi * YX;

#pragma unroll 1
    for (int tap = 0; tap < 27; ++tap) {
        const int kz = tap / 9;
        const int rem = tap - kz * 9;
        const int ky = rem / 3;
        const int kx = rem - ky * 3;
        const int zi = z * STRIDE + kz - 1;
        const int yi = y * STRIDE + ky - 1;
        if ((unsigned)zi >= (unsigned)Zi || (unsigned)yi >= (unsigned)Yi) continue;
        const int xi0 = x * STRIDE + kx - 1;
        const bool okx = (unsigned)xi0 < (unsigned)Xi;
        const int base = zi * YX + yi * Xi + (okx ? xi0 : 0);  // clamped in-bounds addr
        const float* wt0 = wT + tap * COUT;
#pragma unroll 2
        for (int ci = 0; ci < CIN; ++ci) {
            float v = __bfloat162float(in[ci * ZYX + base]);
            v = okx ? v : 0.f;
            const float* wc = wt0 + ci * (27 * COUT);  // uniform -> scalar loads
#pragma unroll
            for (int co = 0; co < COUT; ++co)
                acc[co] = fmaf(v, wc[co], acc[co]);
        }
    }

    const float fm = mk ? 1.f : 0.f;
#pragma unroll
    for (int co = 0; co < COUT; ++co) {
        float yv = fmaf(acc[co], scale[co], shift[co]);
        yv = fmaxf(yv, 0.f) * fm;
        if constexpr (FINAL) outf[co * total + idx] = yv;
        else outb[co * total + idx] = __float2bfloat16(yv);
    }
}

// transposed 3x3x3 conv, stride 2, pad 1 (+output-size handled by caller dims);
// out[o] += w[ci][co][j] * in[ci][(o+1-j)/2] over valid parity/range taps.
template <int CIN, int COUT>
__global__ __launch_bounds__(256) void tconv3_k(
    const bf16* __restrict__ in, const float* __restrict__ wT,
    const float* __restrict__ scale, const float* __restrict__ shift,
    const uint8_t* __restrict__ mask, bf16* __restrict__ out,
    int Zi, int Yi, int Xi, int Zo, int Yo, int Xo) {
    const int total = Zo * Yo * Xo;
    const int idx = blockIdx.x * 256 + threadIdx.x;
    if (idx >= total) return;
    const int x = idx % Xo;
    const int t = idx / Xo;
    const int y = t % Yo;
    const int z = t / Yo;
    const uint8_t mk = mask[idx];

    if (__ballot(mk != 0) == 0ull) {
#pragma unroll
        for (int co = 0; co < COUT; ++co) out[co * total + idx] = __float2bfloat16(0.f);
        return;
    }

    float acc[COUT];
#pragma unroll
    for (int co = 0; co < COUT; ++co) acc[co] = 0.f;

    const int YX = Yi * Xi;
    const int ZYX = Zi * YX;

#pragma unroll 1
    for (int tap = 0; tap < 27; ++tap) {
        const int kz = tap / 9;
        const int rem = tap - kz * 9;
        const int ky = rem / 3;
        const int kx = rem - ky * 3;
        const int tz = z + 1 - kz;
        const int ty = y + 1 - ky;
        if ((tz & 1) || (ty & 1)) continue;
        const int zi = tz >> 1;
        const int yi = ty >> 1;
        if ((unsigned)zi >= (unsigned)Zi || (unsigned)yi >= (unsigned)Yi) continue;
        const int tx = x + 1 - kx;
        const bool okx = ((tx & 1) == 0) && ((unsigned)(tx >> 1) < (unsigned)Xi);
        const int xi = okx ? (tx >> 1) : 0;
        const int base = zi * YX + yi * Xi + xi;
        const float* wt0 = wT + tap * COUT;
#pragma unroll 2
        for (int ci = 0; ci < CIN; ++ci) {
            float v = __bfloat162float(in[ci * ZYX + base]);
            v = okx ? v : 0.f;
            const float* wc = wt0 + ci * (27 * COUT);
#pragma unroll
            for (int co = 0; co < COUT; ++co)
                acc[co] = fmaf(v, wc[co], acc[co]);
        }
    }

    const float fm = mk ? 1.f : 0.f;
#pragma unroll
    for (int co = 0; co < COUT; ++co) {
        float yv = fmaf(acc[co], scale[co], shift[co]);
        yv = fmaxf(yv, 0.f) * fm;
        out[co * total + idx] = __float2bfloat16(yv);
    }
}

inline int nblk(int n) { return (n + 255) / 256; }

}  // namespace

extern "C" void kernel_launch(void* const* d_in, const int* in_sizes, int n_in,
                              void* d_out, int out_size, void* d_ws, size_t ws_size,
                              hipStream_t stream) {
    const float* feats = (const float*)d_in[0];
    const int* coords = (const int*)d_in[1];
    const int NV = in_sizes[0] / 4;

    const float* w1  = (const float*)d_in[3];
    const float* s1  = (const float*)d_in[4];
    const float* b1  = (const float*)d_in[5];
    const float* w2a = (const float*)d_in[6];
    const float* s2a = (const float*)d_in[7];
    const float* b2a = (const float*)d_in[8];
    const float* w2b = (const float*)d_in[9];
    const float* s2b = (const float*)d_in[10];
    const float* b2b = (const float*)d_in[11];
    const float* w3a = (const float*)d_in[12];
    const float* s3a = (const float*)d_in[13];
    const float* b3a = (const float*)d_in[14];
    const float* w3b = (const float*)d_in[15];
    const float* s3b = (const float*)d_in[16];
    const float* b3b = (const float*)d_in[17];
    const float* w4a = (const float*)d_in[18];
    const float* s4a = (const float*)d_in[19];
    const float* b4a = (const float*)d_in[20];
    const float* w4b = (const float*)d_in[21];
    const float* s4b = (const float*)d_in[22];
    const float* b4b = (const float*)d_in[23];
    const float* w5a = (const float*)d_in[24];
    const float* s5a = (const float*)d_in[25];
    const float* b5a = (const float*)d_in[26];
    const float* w5b = (const float*)d_in[27];
    const float* s5b = (const float*)d_in[28];
    const float* b5b = (const float*)d_in[29];

    char* ws = (char*)d_ws;
    size_t off = 0;
    auto alloc = [&](size_t bytes) -> void* {
        void* p = ws + off;
        off = (off + bytes + 255) & ~(size_t)255;
        return p;
    };

    uint8_t* m0 = (uint8_t*)alloc(NZYX0);
    uint8_t* m1 = (uint8_t*)alloc(NZYX0);
    uint8_t* m2 = (uint8_t*)alloc(NZYX2);
    uint8_t* m3 = (uint8_t*)alloc(NZYX3);
    uint8_t* m4 = (uint8_t*)alloc(NZYX4);
    uint8_t* m5 = (uint8_t*)alloc(NZYX0);

    bf16* dense0 = (bf16*)alloc((size_t)4  * NZYX0 * 2);
    bf16* x1     = (bf16*)alloc((size_t)16 * NZYX0 * 2);
    bf16* x2a    = (bf16*)alloc((size_t)32 * NZYX2 * 2);
    bf16* x2b    = (bf16*)alloc((size_t)32 * NZYX2 * 2);
    bf16* x3a    = (bf16*)alloc((size_t)64 * NZYX3 * 2);
    bf16* x3b    = (bf16*)alloc((size_t)64 * NZYX3 * 2);
    bf16* x4a    = (bf16*)alloc((size_t)32 * NZYX4 * 2);
    bf16* x4b    = (bf16*)alloc((size_t)32 * NZYX4 * 2);
    bf16* x5a    = (bf16*)alloc((size_t)32 * NZYX0 * 2);

    float* w1T  = (float*)alloc((size_t)4  * 27 * 16 * 4);
    float* w2aT = (float*)alloc((size_t)16 * 27 * 32 * 4);
    float* w2bT = (float*)alloc((size_t)32 * 27 * 32 * 4);
    float* w3aT = (float*)alloc((size_t)32 * 27 * 64 * 4);
    float* w3bT = (float*)alloc((size_t)64 * 27 * 64 * 4);
    float* w4aT = (float*)alloc((size_t)64 * 27 * 32 * 4);
    float* w4bT = (float*)alloc((size_t)32 * 27 * 32 * 4);
    float* w5aT = (float*)alloc((size_t)32 * 27 * 32 * 4);
    float* w5bT = (float*)alloc((size_t)32 * 27 * 32 * 4);

    if (off > ws_size) {  // workspace too small -> visible sentinel failure
        sentinel_k<<<1, 256, 0, stream>>>((float*)d_out);
        return;
    }

    // ---- stage 0: scatter + weight repack ----
    hipMemsetAsync(dense0, 0, (size_t)4 * NZYX0 * 2, stream);
    hipMemsetAsync(m0, 0, NZYX0, stream);
    scatter_k<<<nblk(NV), 256, 0, stream>>>(feats, coords, dense0, m0, NV);

    repack_conv_k<<<nblk(4 * 16 * 27), 256, 0, stream>>>(w1, w1T, 4, 16);
    repack_conv_k<<<nblk(16 * 32 * 27), 256, 0, stream>>>(w2a, w2aT, 16, 32);
    repack_conv_k<<<nblk(32 * 32 * 27), 256, 0, stream>>>(w2b, w2bT, 32, 32);
    repack_conv_k<<<nblk(32 * 64 * 27), 256, 0, stream>>>(w3a, w3aT, 32, 64);
    repack_conv_k<<<nblk(64 * 64 * 27), 256, 0, stream>>>(w3b, w3bT, 64, 64);
    repack_tconv_k<<<nblk(64 * 32 * 27), 256, 0, stream>>>(w4a, w4aT, 64, 32);
    repack_conv_k<<<nblk(32 * 32 * 27), 256, 0, stream>>>(w4b, w4bT, 32, 32);
    repack_tconv_k<<<nblk(32 * 32 * 27), 256, 0, stream>>>(w5a, w5aT, 32, 32);
    repack_conv_k<<<nblk(32 * 32 * 27), 256, 0, stream>>>(w5b, w5bT, 32, 32);

    // ---- level 1 ----
    dilate_k<<<nblk(NZYX0), 256, 0, stream>>>(m0, m1, Z0, Y0, X0, Z0, Y0, X0, 1);
    conv3_k<4, 16, 1, false><<<nblk(NZYX0), 256, 0, stream>>>(
        dense0, w1T, s1, b1, m1, x1, Z0, Y0, X0, Z0, Y0, X0);

    // ---- level 2 ----
    dilate_k<<<nblk(NZYX2), 256, 0, stream>>>(m1, m2, Z0, Y0, X0, Z2, Y2, X2, 2);
    conv3_k<16, 32, 2, false><<<nblk(NZYX2), 256, 0, stream>>>(
        x1, w2aT, s2a, b2a, m2, x2a, Z0, Y0, X0, Z2, Y2, X2);
    conv3_k<32, 32, 1, false><<<nblk(NZYX2), 256, 0, stream>>>(
        x2a, w2bT, s2b, b2b, m2, x2b, Z2, Y2, X2, Z2, Y2, X2);

    // ---- level 3 ----
    dilate_k<<<nblk(NZYX3), 256, 0, stream>>>(m2, m3, Z2, Y2, X2, Z3, Y3, X3, 2);
    conv3_k<32, 64, 2, false><<<nblk(NZYX3), 256, 0, stream>>>(
        x2b, w3aT, s3a, b3a, m3, x3a, Z2, Y2, X2, Z3, Y3, X3);
    conv3_k<64, 64, 1, false><<<nblk(NZYX3), 256, 0, stream>>>(
        x3a, w3bT, s3b, b3b, m3, x3b, Z3, Y3, X3, Z3, Y3, X3);

    // ---- level 4 (tconv up) ----
    tdilate_k<<<nblk(NZYX4), 256, 0, stream>>>(m3, m4, Z3, Y3, X3, Z4, Y4, X4);
    tconv3_k<64, 32><<<nblk(NZYX4), 256, 0, stream>>>(
        x3b, w4aT, s4a, b4a, m4, x4a, Z3, Y3, X3, Z4, Y4, X4);
    conv3_k<32, 32, 1, false><<<nblk(NZYX4), 256, 0, stream>>>(
        x4a, w4bT, s4b, b4b, m4, x4b, Z4, Y4, X4, Z4, Y4, X4);

    // ---- level 5 (tconv up, outpad (0,3,3)) ----
    tdilate_k<<<nblk(NZYX0), 256, 0, stream>>>(m4, m5, Z4, Y4, X4, Z0, Y0, X0);
    tconv3_k<32, 32><<<nblk(NZYX0), 256, 0, stream>>>(
        x4b, w5aT, s5a, b5a, m5, x5a, Z4, Y4, X4, Z0, Y0, X0);
    conv3_k<32, 32, 1, true><<<nblk(NZYX0), 256, 0, stream>>>(
        x5a, w5bT, s5b, b5b, m5, d_out, Z0, Y0, X0, Z0, Y0, X0);
}

// Round 2
// 1981.778 us; speedup vs baseline: 1.9528x; 1.9528x over previous
//
#include <hip/hip_runtime.h>
#include <hip/hip_bf16.h>
#include <stdint.h>

namespace {

// interior dims per level
constexpr int Z0 = 41, Y0 = 256, X0 = 256;
constexpr int Z2 = 21, Y2 = 128, X2 = 128;
constexpr int Z3 = 11, Y3 = 64,  X3 = 64;
constexpr int Z4 = 21, Y4 = 127, X4 = 127;
constexpr int NV0 = Z0 * Y0 * X0;   // 2,686,976
constexpr int NV2 = Z2 * Y2 * X2;   // 344,064
constexpr int NV3 = Z3 * Y3 * X3;   // 45,056
constexpr int NV4 = Z4 * Y4 * X4;   // 338,709

// padded dims (zero halo of 1; x4b gets +1 extra on high y/x for tconv outpad)
constexpr int ZP0 = 43, YP0 = 258, XP0 = 258; constexpr int NP0 = ZP0 * YP0 * XP0;
constexpr int ZP2 = 23, YP2 = 130, XP2 = 130; constexpr int NP2 = ZP2 * YP2 * XP2;
constexpr int ZP3 = 13, YP3 = 66,  XP3 = 66;  constexpr int NP3 = ZP3 * YP3 * XP3;
constexpr int ZP4 = 23, YP4 = 129, XP4 = 129; constexpr int NP4 = ZP4 * YP4 * XP4;

using bf16 = __hip_bfloat16;
typedef __attribute__((ext_vector_type(8))) short s16x8;
typedef __attribute__((ext_vector_type(4))) float f32x4;

__device__ inline float bflo(unsigned u) { return __builtin_bit_cast(float, u << 16); }
__device__ inline float bfhi(unsigned u) { return __builtin_bit_cast(float, u & 0xffff0000u); }
__device__ inline unsigned f2b(float f) {
    return (unsigned)__builtin_bit_cast(unsigned short, __float2bfloat16(f));
}

__global__ __launch_bounds__(256) void sentinel_k(float* out) { out[0] = 12345.0f; }

// scatter voxels into padded channels-last dense + unpadded mask
__global__ __launch_bounds__(256) void scatter_k(const float* __restrict__ feats,
                                                 const int* __restrict__ coords,
                                                 bf16* __restrict__ dense,
                                                 uint8_t* __restrict__ m0, int n) {
    int v = blockIdx.x * 256 + threadIdx.x;
    if (v >= n) return;
    int z = coords[v * 4 + 1], y = coords[v * 4 + 2], x = coords[v * 4 + 3];
    m0[(z * Y0 + y) * X0 + x] = 1;
    int pp = ((z + 1) * YP0 + (y + 1)) * XP0 + (x + 1);
    uint2 u;
    u.x = f2b(feats[v * 4 + 0]) | (f2b(feats[v * 4 + 1]) << 16);
    u.y = f2b(feats[v * 4 + 2]) | (f2b(feats[v * 4 + 3]) << 16);
    *(uint2*)(dense + (size_t)pp * 4) = u;
}

// zero the halo of a padded channels-last buffer
template <int C>
__global__ __launch_bounds__(256) void halo_zero_k(bf16* __restrict__ buf,
                                                   int Zi, int Yi, int Xi,
                                                   int Zp, int Yp, int Xp) {
    int i = blockIdx.x * 256 + threadIdx.x;
    int tot = Zp * Yp * Xp;
    if (i >= tot) return;
    int x = i % Xp; int t = i / Xp; int y = t % Yp; int z = t / Yp;
    bool halo = (z < 1) | (z > Zi) | (y < 1) | (y > Yi) | (x < 1) | (x > Xi);
    if (!halo) return;
    uint4 zz = make_uint4(0, 0, 0, 0);
    uint4* p = (uint4*)(buf + (size_t)i * C);
#pragma unroll
    for (int j = 0; j < C / 8; ++j) p[j] = zz;
}

// VALU weight repack: wT[(tap*CIN+ci)*COUT+co]
__global__ __launch_bounds__(256) void repack_valu_conv_k(const float* __restrict__ w,
                                                          float* __restrict__ wT,
                                                          int CIN, int COUT) {
    int i = blockIdx.x * 256 + threadIdx.x;
    int n = 27 * CIN * COUT;
    if (i >= n) return;
    int co = i % COUT; int t = i / COUT; int ci = t % CIN; int tap = t / CIN;
    wT[i] = w[(co * CIN + ci) * 27 + tap];
}
__global__ __launch_bounds__(256) void repack_valu_tconv_k(const float* __restrict__ w,
                                                           float* __restrict__ wT,
                                                           int CIN, int COUT) {
    int i = blockIdx.x * 256 + threadIdx.x;
    int n = 27 * CIN * COUT;
    if (i >= n) return;
    int co = i % COUT; int t = i / COUT; int ci = t % CIN; int tap = t / CIN;
    wT[i] = w[(ci * COUT + co) * 27 + tap];
}

// MFMA B-fragment repack (conv weights (COUT,CIN,3,3,3) fp32 -> bf16 frag order)
// frag[((tap*NT+nt)*KT+kt)*64 + lane], elem j: B[k=kt*32+(lane>>4)*8+j][n=nt*16+(lane&15)]
__global__ __launch_bounds__(256) void repack_frag_k(const float* __restrict__ w,
                                                     bf16* __restrict__ wf,
                                                     int CIN, int COUT) {
    int NT = COUT / 16, KT = CIN / 32;
    int i = blockIdx.x * 256 + threadIdx.x;
    int total = 27 * NT * KT * 64;
    if (i >= total) return;
    int lane = i & 63; int t = i >> 6;
    int kt = t % KT; t /= KT; int nt = t % NT; int tap = t / NT;
    int co = nt * 16 + (lane & 15);
    int ci0 = kt * 32 + (lane >> 4) * 8;
    unsigned e[8];
#pragma unroll
    for (int j = 0; j < 8; ++j) e[j] = f2b(w[(co * CIN + ci0 + j) * 27 + tap]);
    uint4 u;
    u.x = e[0] | (e[1] << 16); u.y = e[2] | (e[3] << 16);
    u.z = e[4] | (e[5] << 16); u.w = e[6] | (e[7] << 16);
    ((uint4*)wf)[i] = u;
}

// mask dilation (unpadded masks)
__global__ __launch_bounds__(256) void dilate_k(const uint8_t* __restrict__ in,
                                                uint8_t* __restrict__ out,
                                                int Zi, int Yi, int Xi,
                                                int Zo, int Yo, int Xo, int stride) {
    int idx = blockIdx.x * 256 + threadIdx.x;
    int total = Zo * Yo * Xo;
    if (idx >= total) return;
    int x = idx % Xo; int t = idx / Xo; int y = t % Yo; int z = t / Yo;
    int YX = Yi * Xi;
    uint8_t r = 0;
    for (int kz = 0; kz < 3; ++kz) {
        int zi = z * stride + kz - 1;
        if ((unsigned)zi >= (unsigned)Zi) continue;
        for (int ky = 0; ky < 3; ++ky) {
            int yi = y * stride + ky - 1;
            if ((unsigned)yi >= (unsigned)Yi) continue;
            for (int kx = 0; kx < 3; ++kx) {
                int xi = x * stride + kx - 1;
                if ((unsigned)xi >= (unsigned)Xi) continue;
                r |= in[zi * YX + yi * Xi + xi];
            }
        }
    }
    out[idx] = r ? 1 : 0;
}

__global__ __launch_bounds__(256) void tdilate_k(const uint8_t* __restrict__ in,
                                                 uint8_t* __restrict__ out,
                                                 int Zi, int Yi, int Xi,
                                                 int Zo, int Yo, int Xo) {
    int idx = blockIdx.x * 256 + threadIdx.x;
    int total = Zo * Yo * Xo;
    if (idx >= total) return;
    int x = idx % Xo; int t = idx / Xo; int y = t % Yo; int z = t / Yo;
    int YX = Yi * Xi;
    uint8_t r = 0;
    for (int kz = 0; kz < 3; ++kz) {
        int tz = z + 1 - kz;
        if (tz & 1) continue;
        int zi = tz >> 1;
        if ((unsigned)zi >= (unsigned)Zi) continue;
        for (int ky = 0; ky < 3; ++ky) {
            int ty = y + 1 - ky;
            if (ty & 1) continue;
            int yi = ty >> 1;
            if ((unsigned)yi >= (unsigned)Yi) continue;
            for (int kx = 0; kx < 3; ++kx) {
                int tx = x + 1 - kx;
                if (tx & 1) continue;
                int xi = tx >> 1;
                if ((unsigned)xi >= (unsigned)Xi) continue;
                r |= in[zi * YX + yi * Xi + xi];
            }
        }
    }
    out[idx] = r ? 1 : 0;
}

// VALU direct conv, channels-last padded in/out, fused bn+relu+mask
template <int CIN, int COUT, int STRIDE>
__global__ __launch_bounds__(256) void conv_valu_k(
    const bf16* __restrict__ in, const float* __restrict__ wT,
    const float* __restrict__ scale, const float* __restrict__ shift,
    const uint8_t* __restrict__ mask, bf16* __restrict__ out,
    int Zo, int Yo, int Xo, int Ypi, int Xpi, int Ypo, int Xpo) {
    const int No = Zo * Yo * Xo;
    int idx = blockIdx.x * 256 + threadIdx.x;
    if (idx >= No) return;
    int x = idx % Xo; int t = idx / Xo; int y = t % Yo; int z = t / Yo;
    const int opad = ((z + 1) * Ypo + (y + 1)) * Xpo + (x + 1);
    const uint8_t mk = mask[idx];
    uint4* po = (uint4*)(out + (size_t)opad * COUT);
    if (__ballot(mk != 0) == 0ull) {
        uint4 zz = make_uint4(0, 0, 0, 0);
#pragma unroll
        for (int j = 0; j < COUT / 8; ++j) po[j] = zz;
        return;
    }
    float acc[COUT];
#pragma unroll
    for (int co = 0; co < COUT; ++co) acc[co] = 0.f;
    const int base = (z * STRIDE * Ypi + y * STRIDE) * Xpi + x * STRIDE;
#pragma unroll 1
    for (int tap = 0; tap < 27; ++tap) {
        int kz = tap / 9, r9 = tap - kz * 9, ky = r9 / 3, kx = r9 - ky * 3;
        const bf16* pi = in + (size_t)(base + (kz * Ypi + ky) * Xpi + kx) * CIN;
        const float* wr = wT + tap * CIN * COUT;
        if constexpr (CIN == 4) {
            uint2 u = *(const uint2*)pi;
            float f[4] = {bflo(u.x), bfhi(u.x), bflo(u.y), bfhi(u.y)};
#pragma unroll
            for (int e = 0; e < 4; ++e) {
                const float* w2 = wr + e * COUT;
#pragma unroll
                for (int co = 0; co < COUT; ++co) acc[co] = fmaf(f[e], w2[co], acc[co]);
            }
        } else {
#pragma unroll
            for (int v8 = 0; v8 < CIN / 8; ++v8) {
                uint4 u = *(const uint4*)(pi + v8 * 8);
                unsigned uu[4] = {u.x, u.y, u.z, u.w};
#pragma unroll
                for (int p = 0; p < 4; ++p) {
                    float f0 = bflo(uu[p]), f1 = bfhi(uu[p]);
                    const float* w2 = wr + (v8 * 8 + p * 2) * COUT;
#pragma unroll
                    for (int co = 0; co < COUT; ++co) acc[co] = fmaf(f0, w2[co], acc[co]);
#pragma unroll
                    for (int co = 0; co < COUT; ++co) acc[co] = fmaf(f1, w2[COUT + co], acc[co]);
                }
            }
        }
    }
    const float fm = mk ? 1.f : 0.f;
    unsigned ob[COUT];
#pragma unroll
    for (int co = 0; co < COUT; ++co) {
        float yv = fmaxf(fmaf(acc[co], scale[co], shift[co]), 0.f) * fm;
        ob[co] = f2b(yv);
    }
#pragma unroll
    for (int j = 0; j < COUT / 8; ++j) {
        uint4 u;
        u.x = ob[j * 8 + 0] | (ob[j * 8 + 1] << 16);
        u.y = ob[j * 8 + 2] | (ob[j * 8 + 3] << 16);
        u.z = ob[j * 8 + 4] | (ob[j * 8 + 5] << 16);
        u.w = ob[j * 8 + 6] | (ob[j * 8 + 7] << 16);
        po[j] = u;
    }
}

// VALU transposed conv (stride 2), channels-last padded in/out
template <int CIN, int COUT>
__global__ __launch_bounds__(256) void tconv_valu_k(
    const bf16* __restrict__ in, const float* __restrict__ wT,
    const float* __restrict__ scale, const float* __restrict__ shift,
    const uint8_t* __restrict__ mask, bf16* __restrict__ out,
    int Zo, int Yo, int Xo, int Ypi, int Xpi, int Ypo, int Xpo) {
    const int No = Zo * Yo * Xo;
    int idx = blockIdx.x * 256 + threadIdx.x;
    if (idx >= No) return;
    int x = idx % Xo; int t = idx / Xo; int y = t % Yo; int z = t / Yo;
    const int opad = ((z + 1) * Ypo + (y + 1)) * Xpo + (x + 1);
    const uint8_t mk = mask[idx];
    uint4* po = (uint4*)(out + (size_t)opad * COUT);
    if (__ballot(mk != 0) == 0ull) {
        uint4 zz = make_uint4(0, 0, 0, 0);
#pragma unroll
        for (int j = 0; j < COUT / 8; ++j) po[j] = zz;
        return;
    }
    float acc[COUT];
#pragma unroll
    for (int co = 0; co < COUT; ++co) acc[co] = 0.f;
#pragma unroll 1
    for (int kz = 0; kz < 3; ++kz) {
        int tz = z + 1 - kz;
        if (tz & 1) continue;
        int zi = tz >> 1;
#pragma unroll 1
        for (int ky = 0; ky < 3; ++ky) {
            int ty = y + 1 - ky;
            if (ty & 1) continue;
            int yi = ty >> 1;
#pragma unroll 1
            for (int kx = 0; kx < 3; ++kx) {
                int tx = x + 1 - kx;
                bool okx = !(tx & 1);
                int xi = okx ? (tx >> 1) : 0;
                const bf16* pi = in + (size_t)(((zi + 1) * Ypi + (yi + 1)) * Xpi + (xi + 1)) * CIN;
                const float* wr = wT + (kz * 9 + ky * 3 + kx) * CIN * COUT;
#pragma unroll
                for (int v8 = 0; v8 < CIN / 8; ++v8) {
                    uint4 u = *(const uint4*)(pi + v8 * 8);
                    if (!okx) u = make_uint4(0, 0, 0, 0);
                    unsigned uu[4] = {u.x, u.y, u.z, u.w};
#pragma unroll
                    for (int p = 0; p < 4; ++p) {
                        float f0 = bflo(uu[p]), f1 = bfhi(uu[p]);
                        const float* w2 = wr + (v8 * 8 + p * 2) * COUT;
#pragma unroll
                        for (int co = 0; co < COUT; ++co) acc[co] = fmaf(f0, w2[co], acc[co]);
#pragma unroll
                        for (int co = 0; co < COUT; ++co) acc[co] = fmaf(f1, w2[COUT + co], acc[co]);
                    }
                }
            }
        }
    }
    const float fm = mk ? 1.f : 0.f;
    unsigned ob[COUT];
#pragma unroll
    for (int co = 0; co < COUT; ++co) {
        float yv = fmaxf(fmaf(acc[co], scale[co], shift[co]), 0.f) * fm;
        ob[co] = f2b(yv);
    }
#pragma unroll
    for (int j = 0; j < COUT / 8; ++j) {
        uint4 u;
        u.x = ob[j * 8 + 0] | (ob[j * 8 + 1] << 16);
        u.y = ob[j * 8 + 2] | (ob[j * 8 + 3] << 16);
        u.z = ob[j * 8 + 4] | (ob[j * 8 + 5] << 16);
        u.w = ob[j * 8 + 6] | (ob[j * 8 + 7] << 16);
        po[j] = u;
    }
}

// MFMA implicit-GEMM stride-1 conv. Block = 4 waves x 64 voxels = 256 voxels.
// A: input patches (M=16 voxels, K=32 cin), B: weights frag, 27 taps accumulated.
template <int CIN, int COUT, bool FINAL>
__global__ __launch_bounds__(256) void conv_mfma_k(
    const bf16* __restrict__ in, const bf16* __restrict__ wfrag,
    const float* __restrict__ scale, const float* __restrict__ shift,
    const uint8_t* __restrict__ mask, bf16* __restrict__ out, float* __restrict__ outf,
    int Zo, int Yo, int Xo, int Ypi, int Xpi, int Ypo, int Xpo) {
    constexpr int NT = COUT / 16;
    constexpr int KT = CIN / 32;
    constexpr int NFRAG = 27 * NT * KT * 64;
    constexpr bool BLDS = (NFRAG * 16 <= 60 * 1024);

    const int No = Zo * Yo * Xo;
    const int tid = threadIdx.x;
    const int wv = tid >> 6, lane = tid & 63;
    const int lg = lane >> 4;   // k-group / row-group
    const int lr = lane & 15;   // A-row / B-col

    __shared__ uint4 lw[BLDS ? NFRAG : 1];
    const uint4* gw = (const uint4*)wfrag;
    if constexpr (BLDS) {
        for (int i = tid; i < NFRAG; i += 256) lw[i] = gw[i];
        __syncthreads();
    }

    const int v0 = blockIdx.x * 256 + wv * 64;
    int pA[4];
#pragma unroll
    for (int s = 0; s < 4; ++s) {
        int vr = v0 + s * 16 + lr;
        if (vr >= No) vr = 0;
        int zz = vr / (Yo * Xo); int rr = vr - zz * (Yo * Xo);
        int yy = rr / Xo; int xx = rr - yy * Xo;
        pA[s] = (((zz + 1) * Ypi + (yy + 1)) * Xpi + (xx + 1)) * CIN + lg * 8;
    }

    f32x4 acc[4][NT];
#pragma unroll
    for (int s = 0; s < 4; ++s)
#pragma unroll
        for (int nt = 0; nt < NT; ++nt) acc[s][nt] = (f32x4){0.f, 0.f, 0.f, 0.f};

    for (int tap = 0; tap < 27; ++tap) {
        int kz = tap / 9, r9 = tap - kz * 9, ky = r9 / 3, kx = r9 - ky * 3;
        int toff = (((kz - 1) * Ypi + (ky - 1)) * Xpi + (kx - 1)) * CIN;
        s16x8 bfr[NT][KT];
#pragma unroll
        for (int nt = 0; nt < NT; ++nt)
#pragma unroll
            for (int kt = 0; kt < KT; ++kt) {
                int fi = ((tap * NT + nt) * KT + kt) * 64 + lane;
                uint4 u = BLDS ? lw[fi] : gw[fi];
                bfr[nt][kt] = __builtin_bit_cast(s16x8, u);
            }
#pragma unroll
        for (int s = 0; s < 4; ++s) {
#pragma unroll
            for (int kt = 0; kt < KT; ++kt) {
                uint4 ua = *(const uint4*)(in + pA[s] + toff + kt * 32);
                s16x8 afr = __builtin_bit_cast(s16x8, ua);
#pragma unroll
                for (int nt = 0; nt < NT; ++nt)
                    acc[s][nt] = __builtin_amdgcn_mfma_f32_16x16x32_bf16(
                        afr, bfr[nt][kt], acc[s][nt], 0, 0, 0);
            }
        }
    }

    // epilogue: C layout col=lane&15 (co), row=(lane>>4)*4+reg (voxel)
#pragma unroll
    for (int s = 0; s < 4; ++s) {
        int vb = v0 + s * 16 + lg * 4;
        int opd[4]; float mm[4]; bool ok[4];
#pragma unroll
        for (int r = 0; r < 4; ++r) {
            int v = vb + r;
            ok[r] = v < No;
            int vc = ok[r] ? v : 0;
            mm[r] = (mask[vc] && ok[r]) ? 1.f : 0.f;
            if constexpr (!FINAL) {
                int zz = vc / (Yo * Xo); int rr = vc - zz * (Yo * Xo);
                int yy = rr / Xo; int xx = rr - yy * Xo;
                opd[r] = ((zz + 1) * Ypo + (yy + 1)) * Xpo + (xx + 1);
            } else {
                opd[r] = vc;
            }
        }
#pragma unroll
        for (int nt = 0; nt < NT; ++nt) {
            int co = nt * 16 + lr;
            float sc = scale[co], sh = shift[co];
#pragma unroll
            for (int r = 0; r < 4; ++r) {
                if (!ok[r]) continue;
                float yv = fmaxf(fmaf(acc[s][nt][r], sc, sh), 0.f) * mm[r];
                if constexpr (FINAL)
                    outf[(size_t)co * No + opd[r]] = yv;
                else
                    out[(size_t)opd[r] * COUT + co] = __float2bfloat16(yv);
            }
        }
    }
}

inline int nblk(int n) { return (n + 255) / 256; }

}  // namespace

extern "C" void kernel_launch(void* const* d_in, const int* in_sizes, int n_in,
                              void* d_out, int out_size, void* d_ws, size_t ws_size,
                              hipStream_t stream) {
    const float* feats = (const float*)d_in[0];
    const int* coords = (const int*)d_in[1];
    const int NVOX = in_sizes[0] / 4;

    const float *w1 = (const float*)d_in[3], *s1 = (const float*)d_in[4], *b1 = (const float*)d_in[5];
    const float *w2a = (const float*)d_in[6], *s2a = (const float*)d_in[7], *b2a = (const float*)d_in[8];
    const float *w2b = (const float*)d_in[9], *s2b = (const float*)d_in[10], *b2b = (const float*)d_in[11];
    const float *w3a = (const float*)d_in[12], *s3a = (const float*)d_in[13], *b3a = (const float*)d_in[14];
    const float *w3b = (const float*)d_in[15], *s3b = (const float*)d_in[16], *b3b = (const float*)d_in[17];
    const float *w4a = (const float*)d_in[18], *s4a = (const float*)d_in[19], *b4a = (const float*)d_in[20];
    const float *w4b = (const float*)d_in[21], *s4b = (const float*)d_in[22], *b4b = (const float*)d_in[23];
    const float *w5a = (const float*)d_in[24], *s5a = (const float*)d_in[25], *b5a = (const float*)d_in[26];
    const float *w5b = (const float*)d_in[27], *s5b = (const float*)d_in[28], *b5b = (const float*)d_in[29];

    char* ws = (char*)d_ws;
    size_t off = 0;
    auto alloc = [&](size_t bytes) -> void* {
        void* p = ws + off;
        off = (off + bytes + 255) & ~(size_t)255;
        return p;
    };

    uint8_t* m0 = (uint8_t*)alloc(NV0);
    uint8_t* m1 = (uint8_t*)alloc(NV0);
    uint8_t* m2 = (uint8_t*)alloc(NV2);
    uint8_t* m3 = (uint8_t*)alloc(NV3);
    uint8_t* m4 = (uint8_t*)alloc(NV4);
    uint8_t* m5 = (uint8_t*)alloc(NV0);

    // two ping-pong activation slots (consumer of slot A writes slot B)
    bf16* slot0 = (bf16*)alloc((size_t)NP0 * 32 * 2);   // 183 MB
    bf16* slot1 = (bf16*)alloc((size_t)NP0 * 16 * 2);   // 92 MB

    bf16* dense0 = slot0;  // 4ch  @P0
    bf16* x1     = slot1;  // 16ch @P0
    bf16* x2a    = slot0;  // 32ch @P2
    bf16* x2b    = slot1;  // 32ch @P2
    bf16* x3a    = slot0;  // 64ch @P3
    bf16* x3b    = slot1;  // 64ch @P3
    bf16* x4a    = slot0;  // 32ch @P4
    bf16* x4b    = slot1;  // 32ch @(23,130,130)
    bf16* x5a    = slot0;  // 32ch @P0

    float* w1T  = (float*)alloc(27 * 4 * 16 * 4);
    float* w2aT = (float*)alloc(27 * 16 * 32 * 4);
    float* w3aT = (float*)alloc(27 * 32 * 64 * 4);
    float* w4aT = (float*)alloc(27 * 64 * 32 * 4);
    float* w5aT = (float*)alloc(27 * 32 * 32 * 4);
    bf16* wf2b = (bf16*)alloc(27 * 32 * 32 * 2);
    bf16* wf3b = (bf16*)alloc(27 * 64 * 64 * 2);
    bf16* wf4b = (bf16*)alloc(27 * 32 * 32 * 2);
    bf16* wf5b = (bf16*)alloc(27 * 32 * 32 * 2);

    if (off > ws_size) {
        sentinel_k<<<1, 256, 0, stream>>>((float*)d_out);
        return;
    }

    // stage 0: zero dense input + m0, repack weights
    hipMemsetAsync(dense0, 0, (size_t)NP0 * 4 * 2, stream);
    hipMemsetAsync(m0, 0, NV0, stream);
    repack_valu_conv_k<<<nblk(27 * 4 * 16), 256, 0, stream>>>(w1, w1T, 4, 16);
    repack_valu_conv_k<<<nblk(27 * 16 * 32), 256, 0, stream>>>(w2a, w2aT, 16, 32);
    repack_valu_conv_k<<<nblk(27 * 32 * 64), 256, 0, stream>>>(w3a, w3aT, 32, 64);
    repack_valu_tconv_k<<<nblk(27 * 64 * 32), 256, 0, stream>>>(w4a, w4aT, 64, 32);
    repack_valu_tconv_k<<<nblk(27 * 32 * 32), 256, 0, stream>>>(w5a, w5aT, 32, 32);
    repack_frag_k<<<nblk(27 * 2 * 1 * 64), 256, 0, stream>>>(w2b, wf2b, 32, 32);
    repack_frag_k<<<nblk(27 * 4 * 2 * 64), 256, 0, stream>>>(w3b, wf3b, 64, 64);
    repack_frag_k<<<nblk(27 * 2 * 1 * 64), 256, 0, stream>>>(w4b, wf4b, 32, 32);
    repack_frag_k<<<nblk(27 * 2 * 1 * 64), 256, 0, stream>>>(w5b, wf5b, 32, 32);

    scatter_k<<<nblk(NVOX), 256, 0, stream>>>(feats, coords, dense0, m0, NVOX);

    // level 1
    dilate_k<<<nblk(NV0), 256, 0, stream>>>(m0, m1, Z0, Y0, X0, Z0, Y0, X0, 1);
    halo_zero_k<16><<<nblk(NP0), 256, 0, stream>>>(x1, Z0, Y0, X0, ZP0, YP0, XP0);
    conv_valu_k<4, 16, 1><<<nblk(NV0), 256, 0, stream>>>(
        dense0, w1T, s1, b1, m1, x1, Z0, Y0, X0, YP0, XP0, YP0, XP0);

    // level 2
    dilate_k<<<nblk(NV2), 256, 0, stream>>>(m1, m2, Z0, Y0, X0, Z2, Y2, X2, 2);
    halo_zero_k<32><<<nblk(NP2), 256, 0, stream>>>(x2a, Z2, Y2, X2, ZP2, YP2, XP2);
    conv_valu_k<16, 32, 2><<<nblk(NV2), 256, 0, stream>>>(
        x1, w2aT, s2a, b2a, m2, x2a, Z2, Y2, X2, YP0, XP0, YP2, XP2);
    halo_zero_k<32><<<nblk(NP2), 256, 0, stream>>>(x2b, Z2, Y2, X2, ZP2, YP2, XP2);
    conv_mfma_k<32, 32, false><<<nblk(NV2), 256, 0, stream>>>(
        x2a, wf2b, s2b, b2b, m2, x2b, nullptr, Z2, Y2, X2, YP2, XP2, YP2, XP2);

    // level 3
    dilate_k<<<nblk(NV3), 256, 0, stream>>>(m2, m3, Z2, Y2, X2, Z3, Y3, X3, 2);
    halo_zero_k<64><<<nblk(NP3), 256, 0, stream>>>(x3a, Z3, Y3, X3, ZP3, YP3, XP3);
    conv_valu_k<32, 64, 2><<<nblk(NV3), 256, 0, stream>>>(
        x2b, w3aT, s3a, b3a, m3, x3a, Z3, Y3, X3, YP2, XP2, YP3, XP3);
    halo_zero_k<64><<<nblk(NP3), 256, 0, stream>>>(x3b, Z3, Y3, X3, ZP3, YP3, XP3);
    conv_mfma_k<64, 64, false><<<nblk(NV3), 256, 0, stream>>>(
        x3a, wf3b, s3b, b3b, m3, x3b, nullptr, Z3, Y3, X3, YP3, XP3, YP3, XP3);

    // level 4 (tconv up)
    tdilate_k<<<nblk(NV4), 256, 0, stream>>>(m3, m4, Z3, Y3, X3, Z4, Y4, X4);
    halo_zero_k<32><<<nblk(NP4), 256, 0, stream>>>(x4a, Z4, Y4, X4, ZP4, YP4, XP4);
    tconv_valu_k<64, 32><<<nblk(NV4), 256, 0, stream>>>(
        x3b, w4aT, s4a, b4a, m4, x4a, Z4, Y4, X4, YP3, XP3, YP4, XP4);
    halo_zero_k<32><<<nblk(NP2), 256, 0, stream>>>(x4b, Z4, Y4, X4, ZP2, YP2, XP2);
    conv_mfma_k<32, 32, false><<<nblk(NV4), 256, 0, stream>>>(
        x4a, wf4b, s4b, b4b, m4, x4b, nullptr, Z4, Y4, X4, YP4, XP4, YP2, XP2);

    // level 5 (tconv up, outpad (0,3,3) absorbed by output dims + halo reads)
    tdilate_k<<<nblk(NV0), 256, 0, stream>>>(m4, m5, Z4, Y4, X4, Z0, Y0, X0);
    halo_zero_k<32><<<nblk(NP0), 256, 0, stream>>>(x5a, Z0, Y0, X0, ZP0, YP0, XP0);
    tconv_valu_k<32, 32><<<nblk(NV0), 256, 0, stream>>>(
        x4b, w5aT, s5a, b5a, m5, x5a, Z0, Y0, X0, YP2, XP2, YP0, XP0);
    conv_mfma_k<32, 32, true><<<nblk(NV0), 256, 0, stream>>>(
        x5a, wf5b, s5b, b5b, m5, nullptr, (float*)d_out, Z0, Y0, X0, YP0, XP0, 0, 0);
}

// Round 3
// 1487.441 us; speedup vs baseline: 2.6018x; 1.3323x over previous
//
#include <hip/hip_runtime.h>
#include <hip/hip_bf16.h>
#include <stdint.h>

namespace {

constexpr int Z0 = 41, Y0 = 256, X0 = 256;
constexpr int Z2 = 21, Y2 = 128, X2 = 128;
constexpr int Z3 = 11, Y3 = 64,  X3 = 64;
constexpr int Z4 = 21, Y4 = 127, X4 = 127;
constexpr int NV0 = Z0 * Y0 * X0;
constexpr int NV2 = Z2 * Y2 * X2;
constexpr int NV3 = Z3 * Y3 * X3;
constexpr int NV4 = Z4 * Y4 * X4;

constexpr int ZP0 = 43, YP0 = 258, XP0 = 258; constexpr int NP0 = ZP0 * YP0 * XP0;
constexpr int ZP2 = 23, YP2 = 130, XP2 = 130; constexpr int NP2 = ZP2 * YP2 * XP2;
constexpr int ZP3 = 13, YP3 = 66,  XP3 = 66;  constexpr int NP3 = ZP3 * YP3 * XP3;
constexpr int ZP4 = 23, YP4 = 129, XP4 = 129; constexpr int NP4 = ZP4 * YP4 * XP4;

using bf16 = __hip_bfloat16;
typedef __attribute__((ext_vector_type(8))) short s16x8;
typedef __attribute__((ext_vector_type(4))) float f32x4;

__device__ inline float bflo(unsigned u) { return __builtin_bit_cast(float, u << 16); }
__device__ inline float bfhi(unsigned u) { return __builtin_bit_cast(float, u & 0xffff0000u); }
__device__ inline unsigned f2b(float f) {
    return (unsigned)__builtin_bit_cast(unsigned short, __float2bfloat16(f));
}

// bijective XCD-aware block remap (m204)
__device__ inline int xcd_swz(int bid, int nwg) {
    int q = nwg >> 3, r = nwg & 7;
    int x = bid & 7, j = bid >> 3;
    return (x < r ? x * (q + 1) : r * (q + 1) + (x - r) * q) + j;
}

__global__ __launch_bounds__(256) void sentinel_k(float* out) { out[0] = 12345.0f; }

__global__ __launch_bounds__(256) void scatter_k(const float* __restrict__ feats,
                                                 const int* __restrict__ coords,
                                                 bf16* __restrict__ dense,
                                                 uint8_t* __restrict__ m0, int n) {
    int v = blockIdx.x * 256 + threadIdx.x;
    if (v >= n) return;
    int z = coords[v * 4 + 1], y = coords[v * 4 + 2], x = coords[v * 4 + 3];
    m0[(z * Y0 + y) * X0 + x] = 1;
    int pp = ((z + 1) * YP0 + (y + 1)) * XP0 + (x + 1);
    uint2 u;
    u.x = f2b(feats[v * 4 + 0]) | (f2b(feats[v * 4 + 1]) << 16);
    u.y = f2b(feats[v * 4 + 2]) | (f2b(feats[v * 4 + 3]) << 16);
    *(uint2*)(dense + (size_t)pp * 4) = u;
}

template <int C>
__global__ __launch_bounds__(256) void halo_zero_k(bf16* __restrict__ buf,
                                                   int Zi, int Yi, int Xi,
                                                   int Zp, int Yp, int Xp) {
    int i = blockIdx.x * 256 + threadIdx.x;
    int tot = Zp * Yp * Xp;
    if (i >= tot) return;
    int x = i % Xp; int t = i / Xp; int y = t % Yp; int z = t / Yp;
    bool halo = (z < 1) | (z > Zi) | (y < 1) | (y > Yi) | (x < 1) | (x > Xi);
    if (!halo) return;
    uint4 zz = make_uint4(0, 0, 0, 0);
    uint4* p = (uint4*)(buf + (size_t)i * C);
#pragma unroll
    for (int j = 0; j < C / 8; ++j) p[j] = zz;
}

__global__ __launch_bounds__(256) void repack_valu_conv_k(const float* __restrict__ w,
                                                          float* __restrict__ wT,
                                                          int CIN, int COUT) {
    int i = blockIdx.x * 256 + threadIdx.x;
    int n = 27 * CIN * COUT;
    if (i >= n) return;
    int co = i % COUT; int t = i / COUT; int ci = t % CIN; int tap = t / CIN;
    wT[i] = w[(co * CIN + ci) * 27 + tap];
}

// MFMA B-fragment repack. TRANS=0: w is (COUT,CIN,3,3,3); TRANS=1: (CIN,COUT,3,3,3)
__global__ __launch_bounds__(256) void repack_frag_k(const float* __restrict__ w,
                                                     bf16* __restrict__ wf,
                                                     int CIN, int COUT, int TRANS) {
    int NT = COUT / 16, KT = CIN / 32;
    int i = blockIdx.x * 256 + threadIdx.x;
    int total = 27 * NT * KT * 64;
    if (i >= total) return;
    int lane = i & 63; int t = i >> 6;
    int kt = t % KT; t /= KT; int nt = t % NT; int tap = t / NT;
    int co = nt * 16 + (lane & 15);
    int ci0 = kt * 32 + (lane >> 4) * 8;
    unsigned e[8];
#pragma unroll
    for (int j = 0; j < 8; ++j) {
        int ci = ci0 + j;
        int src = TRANS ? ((ci * COUT + co) * 27 + tap) : ((co * CIN + ci) * 27 + tap);
        e[j] = f2b(w[src]);
    }
    uint4 u;
    u.x = e[0] | (e[1] << 16); u.y = e[2] | (e[3] << 16);
    u.z = e[4] | (e[5] << 16); u.w = e[6] | (e[7] << 16);
    ((uint4*)wf)[i] = u;
}

// L1 frag: K packs (tap,ci): k = tt*4+ci within k-block kb; taps kb*8+tt, tt=lg*2+(j>>2)
__global__ __launch_bounds__(256) void repack_frag_l1_k(const float* __restrict__ w,
                                                        bf16* __restrict__ wf) {
    int i = blockIdx.x * 256 + threadIdx.x;
    if (i >= 256) return;
    int lane = i & 63, kb = i >> 6;
    int lg = lane >> 4, lr = lane & 15;
    unsigned e[8];
#pragma unroll
    for (int j = 0; j < 8; ++j) {
        int tap = kb * 8 + lg * 2 + (j >> 2);
        int ci = j & 3;
        e[j] = (tap < 27) ? f2b(w[(lr * 4 + ci) * 27 + tap]) : 0u;
    }
    uint4 u;
    u.x = e[0] | (e[1] << 16); u.y = e[2] | (e[3] << 16);
    u.z = e[4] | (e[5] << 16); u.w = e[6] | (e[7] << 16);
    ((uint4*)wf)[i] = u;
}

// scalar mask dilation (small grids)
__global__ __launch_bounds__(256) void dilate_k(const uint8_t* __restrict__ in,
                                                uint8_t* __restrict__ out,
                                                int Zi, int Yi, int Xi,
                                                int Zo, int Yo, int Xo, int stride) {
    int idx = blockIdx.x * 256 + threadIdx.x;
    int total = Zo * Yo * Xo;
    if (idx >= total) return;
    int x = idx % Xo; int t = idx / Xo; int y = t % Yo; int z = t / Yo;
    int YX = Yi * Xi;
    uint8_t r = 0;
    for (int kz = 0; kz < 3; ++kz) {
        int zi = z * stride + kz - 1;
        if ((unsigned)zi >= (unsigned)Zi) continue;
        for (int ky = 0; ky < 3; ++ky) {
            int yi = y * stride + ky - 1;
            if ((unsigned)yi >= (unsigned)Yi) continue;
            for (int kx = 0; kx < 3; ++kx) {
                int xi = x * stride + kx - 1;
                if ((unsigned)xi >= (unsigned)Xi) continue;
                r |= in[zi * YX + yi * Xi + xi];
            }
        }
    }
    out[idx] = r ? 1 : 0;
}

// vectorized stride-1 same-size dilation, 4 outputs/thread (X % 4 == 0)
__global__ __launch_bounds__(256) void dilate4_k(const uint8_t* __restrict__ in,
                                                 uint8_t* __restrict__ out,
                                                 int Z, int Y, int X) {
    int ngx = X >> 2;
    int g = blockIdx.x * 256 + threadIdx.x;
    int total = Z * Y * ngx;
    if (g >= total) return;
    int gx = g % ngx; int t = g / ngx; int y = t % Y; int z = t / Y;
    const int YX = Y * X;
    unsigned r = 0;
    for (int kz = 0; kz < 3; ++kz) {
        int zi = z + kz - 1;
        if ((unsigned)zi >= (unsigned)Z) continue;
        for (int ky = 0; ky < 3; ++ky) {
            int yi = y + ky - 1;
            if ((unsigned)yi >= (unsigned)Y) continue;
            const unsigned* rw = (const unsigned*)(in + zi * YX + yi * X);
            unsigned u1 = rw[gx];
            unsigned u0 = gx ? rw[gx - 1] : 0u;
            unsigned u2 = (gx + 1 < ngx) ? rw[gx + 1] : 0u;
            r |= u1 | ((u1 << 8) | (u0 >> 24)) | ((u1 >> 8) | (u2 << 24));
        }
    }
    r |= r >> 4; r |= r >> 2; r |= r >> 1; r &= 0x01010101u;
    ((unsigned*)out)[g] = r;
}

__global__ __launch_bounds__(256) void tdilate_k(const uint8_t* __restrict__ in,
                                                 uint8_t* __restrict__ out,
                                                 int Zi, int Yi, int Xi,
                                                 int Zo, int Yo, int Xo) {
    int idx = blockIdx.x * 256 + threadIdx.x;
    int total = Zo * Yo * Xo;
    if (idx >= total) return;
    int x = idx % Xo; int t = idx / Xo; int y = t % Yo; int z = t / Yo;
    int YX = Yi * Xi;
    uint8_t r = 0;
    for (int kz = 0; kz < 3; ++kz) {
        int tz = z + 1 - kz;
        if (tz & 1) continue;
        int zi = tz >> 1;
        if ((unsigned)zi >= (unsigned)Zi) continue;
        for (int ky = 0; ky < 3; ++ky) {
            int ty = y + 1 - ky;
            if (ty & 1) continue;
            int yi = ty >> 1;
            if ((unsigned)yi >= (unsigned)Yi) continue;
            for (int kx = 0; kx < 3; ++kx) {
                int tx = x + 1 - kx;
                if (tx & 1) continue;
                int xi = tx >> 1;
                if ((unsigned)xi >= (unsigned)Xi) continue;
                r |= in[zi * YX + yi * Xi + xi];
            }
        }
    }
    out[idx] = r ? 1 : 0;
}

// VALU direct conv (used for stride-2 layers L2a, L3a)
template <int CIN, int COUT, int STRIDE>
__global__ __launch_bounds__(256) void conv_valu_k(
    const bf16* __restrict__ in, const float* __restrict__ wT,
    const float* __restrict__ scale, const float* __restrict__ shift,
    const uint8_t* __restrict__ mask, bf16* __restrict__ out,
    int Zo, int Yo, int Xo, int Ypi, int Xpi, int Ypo, int Xpo) {
    const int No = Zo * Yo * Xo;
    int idx = blockIdx.x * 256 + threadIdx.x;
    if (idx >= No) return;
    int x = idx % Xo; int t = idx / Xo; int y = t % Yo; int z = t / Yo;
    const int opad = ((z + 1) * Ypo + (y + 1)) * Xpo + (x + 1);
    const uint8_t mk = mask[idx];
    uint4* po = (uint4*)(out + (size_t)opad * COUT);
    if (__ballot(mk != 0) == 0ull) {
        uint4 zz = make_uint4(0, 0, 0, 0);
#pragma unroll
        for (int j = 0; j < COUT / 8; ++j) po[j] = zz;
        return;
    }
    float acc[COUT];
#pragma unroll
    for (int co = 0; co < COUT; ++co) acc[co] = 0.f;
    const int base = (z * STRIDE * Ypi + y * STRIDE) * Xpi + x * STRIDE;
#pragma unroll 1
    for (int tap = 0; tap < 27; ++tap) {
        int kz = tap / 9, r9 = tap - kz * 9, ky = r9 / 3, kx = r9 - ky * 3;
        const bf16* pi = in + (size_t)(base + (kz * Ypi + ky) * Xpi + kx) * CIN;
        const float* wr = wT + tap * CIN * COUT;
#pragma unroll
        for (int v8 = 0; v8 < CIN / 8; ++v8) {
            uint4 u = *(const uint4*)(pi + v8 * 8);
            unsigned uu[4] = {u.x, u.y, u.z, u.w};
#pragma unroll
            for (int p = 0; p < 4; ++p) {
                float f0 = bflo(uu[p]), f1 = bfhi(uu[p]);
                const float* w2 = wr + (v8 * 8 + p * 2) * COUT;
#pragma unroll
                for (int co = 0; co < COUT; ++co) acc[co] = fmaf(f0, w2[co], acc[co]);
#pragma unroll
                for (int co = 0; co < COUT; ++co) acc[co] = fmaf(f1, w2[COUT + co], acc[co]);
            }
        }
    }
    const float fm = mk ? 1.f : 0.f;
    unsigned ob[COUT];
#pragma unroll
    for (int co = 0; co < COUT; ++co) {
        float yv = fmaxf(fmaf(acc[co], scale[co], shift[co]), 0.f) * fm;
        ob[co] = f2b(yv);
    }
#pragma unroll
    for (int j = 0; j < COUT / 8; ++j) {
        uint4 u;
        u.x = ob[j * 8 + 0] | (ob[j * 8 + 1] << 16);
        u.y = ob[j * 8 + 2] | (ob[j * 8 + 3] << 16);
        u.z = ob[j * 8 + 4] | (ob[j * 8 + 5] << 16);
        u.w = ob[j * 8 + 6] | (ob[j * 8 + 7] << 16);
        po[j] = u;
    }
}

// MFMA implicit-GEMM stride-1 conv, no LDS, B-frags from global (L1/L2-hot).
template <int CIN, int COUT, bool FINAL>
__global__ __launch_bounds__(256, (CIN <= 32 ? 4 : 2)) void conv_mfma_k(
    const bf16* __restrict__ in, const bf16* __restrict__ wfrag,
    const float* __restrict__ scale, const float* __restrict__ shift,
    const uint8_t* __restrict__ mask, bf16* __restrict__ out, float* __restrict__ outf,
    int Zo, int Yo, int Xo, int Ypi, int Xpi, int Ypo, int Xpo) {
    constexpr int NT = COUT / 16;
    constexpr int KT = CIN / 32;
    const int No = Zo * Yo * Xo;
    const int bid = xcd_swz(blockIdx.x, gridDim.x);
    const int tid = threadIdx.x;
    const int wv = tid >> 6, lane = tid & 63;
    const int lg = lane >> 4, lr = lane & 15;
    const int v0 = bid * 256 + wv * 64;
    if (v0 >= No) return;

    // wave-level mask ballot
    int vm = v0 + lane;
    bool mw = (vm < No) && (mask[vm] != 0);
    const bool anywork = (__ballot(mw) != 0ull);

    f32x4 acc[4][NT];
#pragma unroll
    for (int s = 0; s < 4; ++s)
#pragma unroll
        for (int nt = 0; nt < NT; ++nt) acc[s][nt] = (f32x4){0.f, 0.f, 0.f, 0.f};

    const uint4* gw = (const uint4*)wfrag;

    if (anywork) {
        int pA[4];
#pragma unroll
        for (int s = 0; s < 4; ++s) {
            int vr = v0 + s * 16 + lr;
            if (vr >= No) vr = 0;
            int zz = vr / (Yo * Xo); int rr = vr - zz * (Yo * Xo);
            int yy = rr / Xo; int xx = rr - yy * Xo;
            pA[s] = (((zz + 1) * Ypi + (yy + 1)) * Xpi + (xx + 1)) * CIN + lg * 8;
        }
#pragma unroll
        for (int tap = 0; tap < 27; ++tap) {
            const int kz = tap / 9, r9 = tap - kz * 9, ky = r9 / 3, kx = r9 - ky * 3;
            const int toff = (((kz - 1) * Ypi + (ky - 1)) * Xpi + (kx - 1)) * CIN;
            uint4 ub[NT][KT];
#pragma unroll
            for (int nt = 0; nt < NT; ++nt)
#pragma unroll
                for (int kt = 0; kt < KT; ++kt)
                    ub[nt][kt] = gw[((tap * NT + nt) * KT + kt) * 64 + lane];
            uint4 ua[4][KT];
#pragma unroll
            for (int s = 0; s < 4; ++s)
#pragma unroll
                for (int kt = 0; kt < KT; ++kt)
                    ua[s][kt] = *(const uint4*)(in + pA[s] + toff + kt * 32);
#pragma unroll
            for (int s = 0; s < 4; ++s)
#pragma unroll
                for (int kt = 0; kt < KT; ++kt)
#pragma unroll
                    for (int nt = 0; nt < NT; ++nt)
                        acc[s][nt] = __builtin_amdgcn_mfma_f32_16x16x32_bf16(
                            __builtin_bit_cast(s16x8, ua[s][kt]),
                            __builtin_bit_cast(s16x8, ub[nt][kt]), acc[s][nt], 0, 0, 0);
        }
    }

    // epilogue: C row=(lane>>4)*4+reg (voxel), col=lane&15 (cout)
#pragma unroll
    for (int s = 0; s < 4; ++s) {
        const int vb = v0 + s * 16 + lg * 4;
        if constexpr (FINAL) {
            float mm[4];
            bool full = (vb + 3 < No);
#pragma unroll
            for (int r = 0; r < 4; ++r)
                mm[r] = (vb + r < No && mask[vb + r]) ? 1.f : 0.f;
#pragma unroll
            for (int nt = 0; nt < NT; ++nt) {
                int co = nt * 16 + lr;
                float sc = scale[co], sh = shift[co];
                f32x4 o;
#pragma unroll
                for (int r = 0; r < 4; ++r)
                    o[r] = fmaxf(fmaf(acc[s][nt][r], sc, sh), 0.f) * mm[r];
                if (full) {
                    *(f32x4*)(outf + (size_t)co * No + vb) = o;
                } else {
#pragma unroll
                    for (int r = 0; r < 4; ++r)
                        if (vb + r < No) outf[(size_t)co * No + vb + r] = o[r];
                }
            }
        } else {
            int opd[4]; float mm[4]; bool ok[4];
#pragma unroll
            for (int r = 0; r < 4; ++r) {
                int v = vb + r;
                ok[r] = v < No;
                int vc = ok[r] ? v : 0;
                mm[r] = (ok[r] && mask[vc]) ? 1.f : 0.f;
                int zz = vc / (Yo * Xo); int rr = vc - zz * (Yo * Xo);
                int yy = rr / Xo; int xx = rr - yy * Xo;
                opd[r] = ((zz + 1) * Ypo + (yy + 1)) * Xpo + (xx + 1);
            }
#pragma unroll
            for (int nt = 0; nt < NT; ++nt) {
                int co = nt * 16 + lr;
                float sc = scale[co], sh = shift[co];
#pragma unroll
                for (int r = 0; r < 4; ++r) {
                    if (!ok[r]) continue;
                    float yv = fmaxf(fmaf(acc[s][nt][r], sc, sh), 0.f) * mm[r];
                    out[(size_t)opd[r] * COUT + co] = __float2bfloat16(yv);
                }
            }
        }
    }
}

// MFMA transposed conv (stride 2) via parity octants; blockIdx.y = octant
template <int CIN, int COUT>
__global__ __launch_bounds__(256, 4) void tconv_mfma_k(
    const bf16* __restrict__ in, const bf16* __restrict__ wfrag,
    const float* __restrict__ scale, const float* __restrict__ shift,
    const uint8_t* __restrict__ mask, bf16* __restrict__ out,
    int Zo, int Yo, int Xo, int Ypi, int Xpi, int Ypo, int Xpo) {
    constexpr int NT = COUT / 16;
    constexpr int KT = CIN / 32;
    const int oct = blockIdx.y;
    const int pz = oct >> 2, py = (oct >> 1) & 1, px = oct & 1;
    const int Zq = (Zo - pz + 1) >> 1, Yq = (Yo - py + 1) >> 1, Xq = (Xo - px + 1) >> 1;
    const int Nq = Zq * Yq * Xq;
    const int YXq = Yq * Xq;
    const int bid = xcd_swz(blockIdx.x, gridDim.x);
    const int tid = threadIdx.x;
    const int wv = tid >> 6, lane = tid & 63;
    const int lg = lane >> 4, lr = lane & 15;
    const int v0 = bid * 256 + wv * 64;
    if (v0 >= Nq) return;

    // ballot on output mask
    bool mw = false;
    {
        int q = v0 + lane;
        if (q < Nq) {
            int zq = q / YXq; int rr = q - zq * YXq; int yq = rr / Xq; int xq = rr - yq * Xq;
            int zz = 2 * zq + pz, yy = 2 * yq + py, xx = 2 * xq + px;
            mw = mask[(zz * Yo + yy) * Xo + xx] != 0;
        }
    }
    const bool anywork = (__ballot(mw) != 0ull);

    f32x4 acc[4][NT];
#pragma unroll
    for (int s = 0; s < 4; ++s)
#pragma unroll
        for (int nt = 0; nt < NT; ++nt) acc[s][nt] = (f32x4){0.f, 0.f, 0.f, 0.f};

    const uint4* gw = (const uint4*)wfrag;

    if (anywork) {
        int pA[4];
#pragma unroll
        for (int s = 0; s < 4; ++s) {
            int q = v0 + s * 16 + lr;
            if (q >= Nq) q = 0;
            int zq = q / YXq; int rr = q - zq * YXq; int yq = rr / Xq; int xq = rr - yq * Xq;
            pA[s] = (((zq + 1) * Ypi + (yq + 1)) * Xpi + (xq + 1)) * CIN + lg * 8;
        }
        const int nkz = 1 + pz, nky = 1 + py, nkx = 1 + px;
        for (int iz = 0; iz < nkz; ++iz) {
            const int kz = pz ? (iz ? 2 : 0) : 1;
            const int dz = (pz && !iz) ? 1 : 0;
            for (int iy = 0; iy < nky; ++iy) {
                const int ky = py ? (iy ? 2 : 0) : 1;
                const int dy = (py && !iy) ? 1 : 0;
                for (int ix = 0; ix < nkx; ++ix) {
                    const int kx = px ? (ix ? 2 : 0) : 1;
                    const int dx = (px && !ix) ? 1 : 0;
                    const int tap = kz * 9 + ky * 3 + kx;
                    const int toff = ((dz * Ypi + dy) * Xpi + dx) * CIN;
                    uint4 ub[NT][KT];
#pragma unroll
                    for (int nt = 0; nt < NT; ++nt)
#pragma unroll
                        for (int kt = 0; kt < KT; ++kt)
                            ub[nt][kt] = gw[((tap * NT + nt) * KT + kt) * 64 + lane];
                    uint4 ua[4][KT];
#pragma unroll
                    for (int s = 0; s < 4; ++s)
#pragma unroll
                        for (int kt = 0; kt < KT; ++kt)
                            ua[s][kt] = *(const uint4*)(in + pA[s] + toff + kt * 32);
#pragma unroll
                    for (int s = 0; s < 4; ++s)
#pragma unroll
                        for (int kt = 0; kt < KT; ++kt)
#pragma unroll
                            for (int nt = 0; nt < NT; ++nt)
                                acc[s][nt] = __builtin_amdgcn_mfma_f32_16x16x32_bf16(
                                    __builtin_bit_cast(s16x8, ua[s][kt]),
                                    __builtin_bit_cast(s16x8, ub[nt][kt]), acc[s][nt], 0, 0, 0);
                }
            }
        }
    }

#pragma unroll
    for (int s = 0; s < 4; ++s) {
        const int vb = v0 + s * 16 + lg * 4;
        int opd[4]; float mm[4]; bool ok[4];
#pragma unroll
        for (int r = 0; r < 4; ++r) {
            int q = vb + r;
            ok[r] = q < Nq;
            int qc = ok[r] ? q : 0;
            int zq = qc / YXq; int rr = qc - zq * YXq; int yq = rr / Xq; int xq = rr - yq * Xq;
            int zz = 2 * zq + pz, yy = 2 * yq + py, xx = 2 * xq + px;
            mm[r] = (ok[r] && mask[(zz * Yo + yy) * Xo + xx]) ? 1.f : 0.f;
            opd[r] = ((zz + 1) * Ypo + (yy + 1)) * Xpo + (xx + 1);
        }
#pragma unroll
        for (int nt = 0; nt < NT; ++nt) {
            int co = nt * 16 + lr;
            float sc = scale[co], sh = shift[co];
#pragma unroll
            for (int r = 0; r < 4; ++r) {
                if (!ok[r]) continue;
                float yv = fmaxf(fmaf(acc[s][nt][r], sc, sh), 0.f) * mm[r];
                out[(size_t)opd[r] * COUT + co] = __float2bfloat16(yv);
            }
        }
    }
}

// L1 conv (4->16) with taps packed into K: K-block kb covers taps kb*8..kb*8+7
__global__ __launch_bounds__(256, 4) void conv_l1_mfma_k(
    const bf16* __restrict__ in, const bf16* __restrict__ wfrag,
    const float* __restrict__ scale, const float* __restrict__ shift,
    const uint8_t* __restrict__ mask, bf16* __restrict__ out,
    int Zo, int Yo, int Xo, int Ypi, int Xpi, int Ypo, int Xpo) {
    const int No = Zo * Yo * Xo;
    const int bid = xcd_swz(blockIdx.x, gridDim.x);
    const int tid = threadIdx.x;
    const int wv = tid >> 6, lane = tid & 63;
    const int lg = lane >> 4, lr = lane & 15;
    const int v0 = bid * 256 + wv * 64;
    if (v0 >= No) return;

    int vm = v0 + lane;
    bool mw = (vm < No) && (mask[vm] != 0);
    const bool anywork = (__ballot(mw) != 0ull);

    f32x4 acc[4];
#pragma unroll
    for (int s = 0; s < 4; ++s) acc[s] = (f32x4){0.f, 0.f, 0.f, 0.f};

    if (anywork) {
        const uint4* gw = (const uint4*)wfrag;
        uint4 bu[4];
#pragma unroll
        for (int kb = 0; kb < 4; ++kb) bu[kb] = gw[kb * 64 + lane];

        // per-lane tap voxel-offsets (taps kb*8 + lg*2 + u); invalid taps have zero B
        int vtf[4][2];
#pragma unroll
        for (int kb = 0; kb < 4; ++kb)
#pragma unroll
            for (int u = 0; u < 2; ++u) {
                int tp = kb * 8 + lg * 2 + u;
                int kz = tp / 9, r9 = tp - kz * 9, ky = r9 / 3, kx = r9 - ky * 3;
                vtf[kb][u] = (tp < 27) ? (((kz - 1) * Ypi + (ky - 1)) * Xpi + (kx - 1)) : 0;
            }

        int pV[4];
#pragma unroll
        for (int s = 0; s < 4; ++s) {
            int vr = v0 + s * 16 + lr;
            if (vr >= No) vr = 0;
            int zz = vr / (Yo * Xo); int rr = vr - zz * (Yo * Xo);
            int yy = rr / Xo; int xx = rr - yy * Xo;
            pV[s] = ((zz + 1) * Ypi + (yy + 1)) * Xpi + (xx + 1);
        }

#pragma unroll
        for (int kb = 0; kb < 4; ++kb) {
#pragma unroll
            for (int s = 0; s < 4; ++s) {
                uint2 a0 = *(const uint2*)(in + (size_t)(pV[s] + vtf[kb][0]) * 4);
                uint2 a1 = *(const uint2*)(in + (size_t)(pV[s] + vtf[kb][1]) * 4);
                int4 ai; ai.x = a0.x; ai.y = a0.y; ai.z = a1.x; ai.w = a1.y;
                acc[s] = __builtin_amdgcn_mfma_f32_16x16x32_bf16(
                    __builtin_bit_cast(s16x8, ai),
                    __builtin_bit_cast(s16x8, bu[kb]), acc[s], 0, 0, 0);
            }
        }
    }

#pragma unroll
    for (int s = 0; s < 4; ++s) {
        const int vb = v0 + s * 16 + lg * 4;
        int co = lr;
        float sc = scale[co], sh = shift[co];
#pragma unroll
        for (int r = 0; r < 4; ++r) {
            int v = vb + r;
            if (v >= No) continue;
            float mm = mask[v] ? 1.f : 0.f;
            int zz = v / (Yo * Xo); int rr = v - zz * (Yo * Xo);
            int yy = rr / Xo; int xx = rr - yy * Xo;
            int opd = ((zz + 1) * Ypo + (yy + 1)) * Xpo + (xx + 1);
            float yv = fmaxf(fmaf(acc[s][r], sc, sh), 0.f) * mm;
            out[(size_t)opd * 16 + co] = __float2bfloat16(yv);
        }
    }
}

inline int nblk(int n) { return (n + 255) / 256; }

}  // namespace

extern "C" void kernel_launch(void* const* d_in, const int* in_sizes, int n_in,
                              void* d_out, int out_size, void* d_ws, size_t ws_size,
                              hipStream_t stream) {
    const float* feats = (const float*)d_in[0];
    const int* coords = (const int*)d_in[1];
    const int NVOX = in_sizes[0] / 4;

    const float *w1 = (const float*)d_in[3], *s1 = (const float*)d_in[4], *b1 = (const float*)d_in[5];
    const float *w2a = (const float*)d_in[6], *s2a = (const float*)d_in[7], *b2a = (const float*)d_in[8];
    const float *w2b = (const float*)d_in[9], *s2b = (const float*)d_in[10], *b2b = (const float*)d_in[11];
    const float *w3a = (const float*)d_in[12], *s3a = (const float*)d_in[13], *b3a = (const float*)d_in[14];
    const float *w3b = (const float*)d_in[15], *s3b = (const float*)d_in[16], *b3b = (const float*)d_in[17];
    const float *w4a = (const float*)d_in[18], *s4a = (const float*)d_in[19], *b4a = (const float*)d_in[20];
    const float *w4b = (const float*)d_in[21], *s4b = (const float*)d_in[22], *b4b = (const float*)d_in[23];
    const float *w5a = (const float*)d_in[24], *s5a = (const float*)d_in[25], *b5a = (const float*)d_in[26];
    const float *w5b = (const float*)d_in[27], *s5b = (const float*)d_in[28], *b5b = (const float*)d_in[29];

    char* ws = (char*)d_ws;
    size_t off = 0;
    auto alloc = [&](size_t bytes) -> void* {
        void* p = ws + off;
        off = (off + bytes + 255) & ~(size_t)255;
        return p;
    };

    uint8_t* m0 = (uint8_t*)alloc(NV0);
    uint8_t* m1 = (uint8_t*)alloc(NV0);
    uint8_t* m2 = (uint8_t*)alloc(NV2);
    uint8_t* m3 = (uint8_t*)alloc(NV3);
    uint8_t* m4 = (uint8_t*)alloc(NV4);
    uint8_t* m5 = (uint8_t*)alloc(NV0);

    bf16* slot0 = (bf16*)alloc((size_t)NP0 * 32 * 2);
    bf16* slot1 = (bf16*)alloc((size_t)NP0 * 16 * 2);

    bf16* dense0 = slot0;  // 4ch  @P0
    bf16* x1     = slot1;  // 16ch @P0
    bf16* x2a    = slot0;  // 32ch @P2
    bf16* x2b    = slot1;  // 32ch @P2
    bf16* x3a    = slot0;  // 64ch @P3
    bf16* x3b    = slot1;  // 64ch @P3
    bf16* x4a    = slot0;  // 32ch @P4
    bf16* x4b    = slot1;  // 32ch @(23,130,130)
    bf16* x5a    = slot0;  // 32ch @P0

    float* w2aT = (float*)alloc(27 * 16 * 32 * 4);
    float* w3aT = (float*)alloc(27 * 32 * 64 * 4);
    bf16* wfL1 = (bf16*)alloc(4 * 64 * 8 * 2);          // 4 KB
    bf16* wf2b = (bf16*)alloc((size_t)27 * 2 * 1 * 64 * 16);
    bf16* wf3b = (bf16*)alloc((size_t)27 * 4 * 2 * 64 * 16);
    bf16* wf4a = (bf16*)alloc((size_t)27 * 2 * 2 * 64 * 16);
    bf16* wf4b = (bf16*)alloc((size_t)27 * 2 * 1 * 64 * 16);
    bf16* wf5a = (bf16*)alloc((size_t)27 * 2 * 1 * 64 * 16);
    bf16* wf5b = (bf16*)alloc((size_t)27 * 2 * 1 * 64 * 16);

    if (off > ws_size) {
        sentinel_k<<<1, 256, 0, stream>>>((float*)d_out);
        return;
    }

    // stage 0
    hipMemsetAsync(dense0, 0, (size_t)NP0 * 4 * 2, stream);
    hipMemsetAsync(m0, 0, NV0, stream);
    repack_valu_conv_k<<<nblk(27 * 16 * 32), 256, 0, stream>>>(w2a, w2aT, 16, 32);
    repack_valu_conv_k<<<nblk(27 * 32 * 64), 256, 0, stream>>>(w3a, w3aT, 32, 64);
    repack_frag_l1_k<<<1, 256, 0, stream>>>(w1, wfL1);
    repack_frag_k<<<nblk(27 * 2 * 64), 256, 0, stream>>>(w2b, wf2b, 32, 32, 0);
    repack_frag_k<<<nblk(27 * 8 * 64), 256, 0, stream>>>(w3b, wf3b, 64, 64, 0);
    repack_frag_k<<<nblk(27 * 4 * 64), 256, 0, stream>>>(w4a, wf4a, 64, 32, 1);
    repack_frag_k<<<nblk(27 * 2 * 64), 256, 0, stream>>>(w4b, wf4b, 32, 32, 0);
    repack_frag_k<<<nblk(27 * 2 * 64), 256, 0, stream>>>(w5a, wf5a, 32, 32, 1);
    repack_frag_k<<<nblk(27 * 2 * 64), 256, 0, stream>>>(w5b, wf5b, 32, 32, 0);

    scatter_k<<<nblk(NVOX), 256, 0, stream>>>(feats, coords, dense0, m0, NVOX);

    // level 1
    dilate4_k<<<nblk(NV0 / 4), 256, 0, stream>>>(m0, m1, Z0, Y0, X0);
    halo_zero_k<16><<<nblk(NP0), 256, 0, stream>>>(x1, Z0, Y0, X0, ZP0, YP0, XP0);
    conv_l1_mfma_k<<<nblk(NV0), 256, 0, stream>>>(
        dense0, wfL1, s1, b1, m1, x1, Z0, Y0, X0, YP0, XP0, YP0, XP0);

    // level 2
    dilate_k<<<nblk(NV2), 256, 0, stream>>>(m1, m2, Z0, Y0, X0, Z2, Y2, X2, 2);
    halo_zero_k<32><<<nblk(NP2), 256, 0, stream>>>(x2a, Z2, Y2, X2, ZP2, YP2, XP2);
    conv_valu_k<16, 32, 2><<<nblk(NV2), 256, 0, stream>>>(
        x1, w2aT, s2a, b2a, m2, x2a, Z2, Y2, X2, YP0, XP0, YP2, XP2);
    halo_zero_k<32><<<nblk(NP2), 256, 0, stream>>>(x2b, Z2, Y2, X2, ZP2, YP2, XP2);
    conv_mfma_k<32, 32, false><<<nblk(NV2), 256, 0, stream>>>(
        x2a, wf2b, s2b, b2b, m2, x2b, nullptr, Z2, Y2, X2, YP2, XP2, YP2, XP2);

    // level 3
    dilate_k<<<nblk(NV3), 256, 0, stream>>>(m2, m3, Z2, Y2, X2, Z3, Y3, X3, 2);
    halo_zero_k<64><<<nblk(NP3), 256, 0, stream>>>(x3a, Z3, Y3, X3, ZP3, YP3, XP3);
    conv_valu_k<32, 64, 2><<<nblk(NV3), 256, 0, stream>>>(
        x2b, w3aT, s3a, b3a, m3, x3a, Z3, Y3, X3, YP2, XP2, YP3, XP3);
    halo_zero_k<64><<<nblk(NP3), 256, 0, stream>>>(x3b, Z3, Y3, X3, ZP3, YP3, XP3);
    conv_mfma_k<64, 64, false><<<nblk(NV3), 256, 0, stream>>>(
        x3a, wf3b, s3b, b3b, m3, x3b, nullptr, Z3, Y3, X3, YP3, XP3, YP3, XP3);

    // level 4 (tconv up via parity octants)
    tdilate_k<<<nblk(NV4), 256, 0, stream>>>(m3, m4, Z3, Y3, X3, Z4, Y4, X4);
    halo_zero_k<32><<<nblk(NP4), 256, 0, stream>>>(x4a, Z4, Y4, X4, ZP4, YP4, XP4);
    {
        int maxNq = ((Z4 + 1) >> 1) * ((Y4 + 1) >> 1) * ((X4 + 1) >> 1);
        dim3 g(nblk(maxNq), 8);
        tconv_mfma_k<64, 32><<<g, 256, 0, stream>>>(
            x3b, wf4a, s4a, b4a, m4, x4a, Z4, Y4, X4, YP3, XP3, YP4, XP4);
    }
    halo_zero_k<32><<<nblk(NP2), 256, 0, stream>>>(x4b, Z4, Y4, X4, ZP2, YP2, XP2);
    conv_mfma_k<32, 32, false><<<nblk(NV4), 256, 0, stream>>>(
        x4a, wf4b, s4b, b4b, m4, x4b, nullptr, Z4, Y4, X4, YP4, XP4, YP2, XP2);

    // level 5 (tconv up, outpad (0,3,3) via extra zero halo rows in x4b)
    tdilate_k<<<nblk(NV0), 256, 0, stream>>>(m4, m5, Z4, Y4, X4, Z0, Y0, X0);
    halo_zero_k<32><<<nblk(NP0), 256, 0, stream>>>(x5a, Z0, Y0, X0, ZP0, YP0, XP0);
    {
        int maxNq = ((Z0 + 1) >> 1) * (Y0 >> 1) * (X0 >> 1);
        dim3 g(nblk(maxNq), 8);
        tconv_mfma_k<32, 32><<<g, 256, 0, stream>>>(
            x4b, wf5a, s5a, b5a, m5, x5a, Z0, Y0, X0, YP2, XP2, YP0, XP0);
    }
    conv_mfma_k<32, 32, true><<<nblk(NV0), 256, 0, stream>>>(
        x5a, wf5b, s5b, b5b, m5, nullptr, (float*)d_out, Z0, Y0, X0, YP0, XP0, 0, 0);
}

// Round 4
// 1214.166 us; speedup vs baseline: 3.1873x; 1.2251x over previous
//
#include <hip/hip_runtime.h>
#include <hip/hip_bf16.h>
#include <stdint.h>

namespace {

constexpr int Z0 = 41, Y0 = 256, X0 = 256;
constexpr int Z2 = 21, Y2 = 128, X2 = 128;
constexpr int Z3 = 11, Y3 = 64,  X3 = 64;
constexpr int Z4 = 21, Y4 = 127, X4 = 127;
constexpr int NV0 = Z0 * Y0 * X0;
constexpr int NV2 = Z2 * Y2 * X2;
constexpr int NV3 = Z3 * Y3 * X3;
constexpr int NV4 = Z4 * Y4 * X4;

constexpr int ZP0 = 43, YP0 = 258, XP0 = 258; constexpr int NP0 = ZP0 * YP0 * XP0;
constexpr int ZP2 = 23, YP2 = 130, XP2 = 130; constexpr int NP2 = ZP2 * YP2 * XP2;
constexpr int ZP3 = 13, YP3 = 66,  XP3 = 66;  constexpr int NP3 = ZP3 * YP3 * XP3;
constexpr int ZP4 = 23, YP4 = 129, XP4 = 129; constexpr int NP4 = ZP4 * YP4 * XP4;

using bf16 = __hip_bfloat16;
typedef __attribute__((ext_vector_type(8))) short s16x8;
typedef __attribute__((ext_vector_type(4))) float f32x4;

__device__ inline float bflo(unsigned u) { return __builtin_bit_cast(float, u << 16); }
__device__ inline float bfhi(unsigned u) { return __builtin_bit_cast(float, u & 0xffff0000u); }
__device__ inline unsigned f2b(float f) {
    return (unsigned)__builtin_bit_cast(unsigned short, __float2bfloat16(f));
}

__device__ inline int xcd_swz(int bid, int nwg) {
    int q = nwg >> 3, r = nwg & 7;
    int x = bid & 7, j = bid >> 3;
    return (x < r ? x * (q + 1) : r * (q + 1) + (x - r) * q) + j;
}

__device__ inline void glds16(const bf16* g, void* l) {
    __builtin_amdgcn_global_load_lds(
        (const __attribute__((address_space(1))) void*)g,
        (__attribute__((address_space(3))) void*)l, 16, 0, 0);
}

__global__ __launch_bounds__(256) void sentinel_k(float* out) { out[0] = 12345.0f; }

__global__ __launch_bounds__(256) void scatter_k(const float* __restrict__ feats,
                                                 const int* __restrict__ coords,
                                                 bf16* __restrict__ dense,
                                                 uint8_t* __restrict__ m0, int n) {
    int v = blockIdx.x * 256 + threadIdx.x;
    if (v >= n) return;
    int z = coords[v * 4 + 1], y = coords[v * 4 + 2], x = coords[v * 4 + 3];
    m0[(z * Y0 + y) * X0 + x] = 1;
    int pp = ((z + 1) * YP0 + (y + 1)) * XP0 + (x + 1);
    uint2 u;
    u.x = f2b(feats[v * 4 + 0]) | (f2b(feats[v * 4 + 1]) << 16);
    u.y = f2b(feats[v * 4 + 2]) | (f2b(feats[v * 4 + 3]) << 16);
    *(uint2*)(dense + (size_t)pp * 4) = u;
}

template <int C>
__global__ __launch_bounds__(256) void halo_zero_k(bf16* __restrict__ buf,
                                                   int Zi, int Yi, int Xi,
                                                   int Zp, int Yp, int Xp) {
    int i = blockIdx.x * 256 + threadIdx.x;
    int tot = Zp * Yp * Xp;
    if (i >= tot) return;
    int x = i % Xp; int t = i / Xp; int y = t % Yp; int z = t / Yp;
    bool halo = (z < 1) | (z > Zi) | (y < 1) | (y > Yi) | (x < 1) | (x > Xi);
    if (!halo) return;
    uint4 zz = make_uint4(0, 0, 0, 0);
    uint4* p = (uint4*)(buf + (size_t)i * C);
#pragma unroll
    for (int j = 0; j < C / 8; ++j) p[j] = zz;
}

__global__ __launch_bounds__(256) void repack_valu_conv_k(const float* __restrict__ w,
                                                          float* __restrict__ wT,
                                                          int CIN, int COUT) {
    int i = blockIdx.x * 256 + threadIdx.x;
    int n = 27 * CIN * COUT;
    if (i >= n) return;
    int co = i % COUT; int t = i / COUT; int ci = t % CIN; int tap = t / CIN;
    wT[i] = w[(co * CIN + ci) * 27 + tap];
}

__global__ __launch_bounds__(256) void repack_frag_k(const float* __restrict__ w,
                                                     bf16* __restrict__ wf,
                                                     int CIN, int COUT, int TRANS) {
    int NT = COUT / 16, KT = CIN / 32;
    int i = blockIdx.x * 256 + threadIdx.x;
    int total = 27 * NT * KT * 64;
    if (i >= total) return;
    int lane = i & 63; int t = i >> 6;
    int kt = t % KT; t /= KT; int nt = t % NT; int tap = t / NT;
    int co = nt * 16 + (lane & 15);
    int ci0 = kt * 32 + (lane >> 4) * 8;
    unsigned e[8];
#pragma unroll
    for (int j = 0; j < 8; ++j) {
        int ci = ci0 + j;
        int src = TRANS ? ((ci * COUT + co) * 27 + tap) : ((co * CIN + ci) * 27 + tap);
        e[j] = f2b(w[src]);
    }
    uint4 u;
    u.x = e[0] | (e[1] << 16); u.y = e[2] | (e[3] << 16);
    u.z = e[4] | (e[5] << 16); u.w = e[6] | (e[7] << 16);
    ((uint4*)wf)[i] = u;
}

__global__ __launch_bounds__(256) void repack_frag_l1_k(const float* __restrict__ w,
                                                        bf16* __restrict__ wf) {
    int i = blockIdx.x * 256 + threadIdx.x;
    if (i >= 256) return;
    int lane = i & 63, kb = i >> 6;
    int lg = lane >> 4, lr = lane & 15;
    unsigned e[8];
#pragma unroll
    for (int j = 0; j < 8; ++j) {
        int tap = kb * 8 + lg * 2 + (j >> 2);
        int ci = j & 3;
        e[j] = (tap < 27) ? f2b(w[(lr * 4 + ci) * 27 + tap]) : 0u;
    }
    uint4 u;
    u.x = e[0] | (e[1] << 16); u.y = e[2] | (e[3] << 16);
    u.z = e[4] | (e[5] << 16); u.w = e[6] | (e[7] << 16);
    ((uint4*)wf)[i] = u;
}

__global__ __launch_bounds__(256) void dilate_k(const uint8_t* __restrict__ in,
                                                uint8_t* __restrict__ out,
                                                int Zi, int Yi, int Xi,
                                                int Zo, int Yo, int Xo, int stride) {
    int idx = blockIdx.x * 256 + threadIdx.x;
    int total = Zo * Yo * Xo;
    if (idx >= total) return;
    int x = idx % Xo; int t = idx / Xo; int y = t % Yo; int z = t / Yo;
    int YX = Yi * Xi;
    uint8_t r = 0;
    for (int kz = 0; kz < 3; ++kz) {
        int zi = z * stride + kz - 1;
        if ((unsigned)zi >= (unsigned)Zi) continue;
        for (int ky = 0; ky < 3; ++ky) {
            int yi = y * stride + ky - 1;
            if ((unsigned)yi >= (unsigned)Yi) continue;
            for (int kx = 0; kx < 3; ++kx) {
                int xi = x * stride + kx - 1;
                if ((unsigned)xi >= (unsigned)Xi) continue;
                r |= in[zi * YX + yi * Xi + xi];
            }
        }
    }
    out[idx] = r ? 1 : 0;
}

__global__ __launch_bounds__(256) void dilate4_k(const uint8_t* __restrict__ in,
                                                 uint8_t* __restrict__ out,
                                                 int Z, int Y, int X) {
    int ngx = X >> 2;
    int g = blockIdx.x * 256 + threadIdx.x;
    int total = Z * Y * ngx;
    if (g >= total) return;
    int gx = g % ngx; int t = g / ngx; int y = t % Y; int z = t / Y;
    const int YX = Y * X;
    unsigned r = 0;
    for (int kz = 0; kz < 3; ++kz) {
        int zi = z + kz - 1;
        if ((unsigned)zi >= (unsigned)Z) continue;
        for (int ky = 0; ky < 3; ++ky) {
            int yi = y + ky - 1;
            if ((unsigned)yi >= (unsigned)Y) continue;
            const unsigned* rw = (const unsigned*)(in + zi * YX + yi * X);
            unsigned u1 = rw[gx];
            unsigned u0 = gx ? rw[gx - 1] : 0u;
            unsigned u2 = (gx + 1 < ngx) ? rw[gx + 1] : 0u;
            r |= u1 | ((u1 << 8) | (u0 >> 24)) | ((u1 >> 8) | (u2 << 24));
        }
    }
    r |= r >> 4; r |= r >> 2; r |= r >> 1; r &= 0x01010101u;
    ((unsigned*)out)[g] = r;
}

__global__ __launch_bounds__(256) void tdilate_k(const uint8_t* __restrict__ in,
                                                 uint8_t* __restrict__ out,
                                                 int Zi, int Yi, int Xi,
                                                 int Zo, int Yo, int Xo) {
    int idx = blockIdx.x * 256 + threadIdx.x;
    int total = Zo * Yo * Xo;
    if (idx >= total) return;
    int x = idx % Xo; int t = idx / Xo; int y = t % Yo; int z = t / Yo;
    int YX = Yi * Xi;
    uint8_t r = 0;
    for (int kz = 0; kz < 3; ++kz) {
        int tz = z + 1 - kz;
        if (tz & 1) continue;
        int zi = tz >> 1;
        if ((unsigned)zi >= (unsigned)Zi) continue;
        for (int ky = 0; ky < 3; ++ky) {
            int ty = y + 1 - ky;
            if (ty & 1) continue;
            int yi = ty >> 1;
            if ((unsigned)yi >= (unsigned)Yi) continue;
            for (int kx = 0; kx < 3; ++kx) {
                int tx = x + 1 - kx;
                if (tx & 1) continue;
                int xi = tx >> 1;
                if ((unsigned)xi >= (unsigned)Xi) continue;
                r |= in[zi * YX + yi * Xi + xi];
            }
        }
    }
    out[idx] = r ? 1 : 0;
}

template <int CIN, int COUT, int STRIDE>
__global__ __launch_bounds__(256) void conv_valu_k(
    const bf16* __restrict__ in, const float* __restrict__ wT,
    const float* __restrict__ scale, const float* __restrict__ shift,
    const uint8_t* __restrict__ mask, bf16* __restrict__ out,
    int Zo, int Yo, int Xo, int Ypi, int Xpi, int Ypo, int Xpo) {
    const int No = Zo * Yo * Xo;
    int idx = blockIdx.x * 256 + threadIdx.x;
    if (idx >= No) return;
    int x = idx % Xo; int t = idx / Xo; int y = t % Yo; int z = t / Yo;
    const int opad = ((z + 1) * Ypo + (y + 1)) * Xpo + (x + 1);
    const uint8_t mk = mask[idx];
    uint4* po = (uint4*)(out + (size_t)opad * COUT);
    if (__ballot(mk != 0) == 0ull) {
        uint4 zz = make_uint4(0, 0, 0, 0);
#pragma unroll
        for (int j = 0; j < COUT / 8; ++j) po[j] = zz;
        return;
    }
    float acc[COUT];
#pragma unroll
    for (int co = 0; co < COUT; ++co) acc[co] = 0.f;
    const int base = (z * STRIDE * Ypi + y * STRIDE) * Xpi + x * STRIDE;
#pragma unroll 1
    for (int tap = 0; tap < 27; ++tap) {
        int kz = tap / 9, r9 = tap - kz * 9, ky = r9 / 3, kx = r9 - ky * 3;
        const bf16* pi = in + (size_t)(base + (kz * Ypi + ky) * Xpi + kx) * CIN;
        const float* wr = wT + tap * CIN * COUT;
#pragma unroll
        for (int v8 = 0; v8 < CIN / 8; ++v8) {
            uint4 u = *(const uint4*)(pi + v8 * 8);
            unsigned uu[4] = {u.x, u.y, u.z, u.w};
#pragma unroll
            for (int p = 0; p < 4; ++p) {
                float f0 = bflo(uu[p]), f1 = bfhi(uu[p]);
                const float* w2 = wr + (v8 * 8 + p * 2) * COUT;
#pragma unroll
                for (int co = 0; co < COUT; ++co) acc[co] = fmaf(f0, w2[co], acc[co]);
#pragma unroll
                for (int co = 0; co < COUT; ++co) acc[co] = fmaf(f1, w2[COUT + co], acc[co]);
            }
        }
    }
    const float fm = mk ? 1.f : 0.f;
    unsigned ob[COUT];
#pragma unroll
    for (int co = 0; co < COUT; ++co) {
        float yv = fmaxf(fmaf(acc[co], scale[co], shift[co]), 0.f) * fm;
        ob[co] = f2b(yv);
    }
#pragma unroll
    for (int j = 0; j < COUT / 8; ++j) {
        uint4 u;
        u.x = ob[j * 8 + 0] | (ob[j * 8 + 1] << 16);
        u.y = ob[j * 8 + 2] | (ob[j * 8 + 3] << 16);
        u.z = ob[j * 8 + 4] | (ob[j * 8 + 5] << 16);
        u.w = ob[j * 8 + 6] | (ob[j * 8 + 7] << 16);
        po[j] = u;
    }
}

// LDS-tiled MFMA stride-1 conv, CIN=COUT=32. Block 512 thr = 8 waves,
// tile 4z x 4y x 32x outputs; halo 6x6x34 voxels staged via global_load_lds.
template <bool FINAL>
__global__ __launch_bounds__(512, 4) void conv_lds_k(
    const bf16* __restrict__ in, const bf16* __restrict__ wfrag,
    const float* __restrict__ scale, const float* __restrict__ shift,
    const uint8_t* __restrict__ mask, bf16* __restrict__ out, float* __restrict__ outf,
    int Zo, int Yo, int Xo, int Ypi, int Xpi, int Ypo, int Xpo, int nx, int ny) {
    constexpr int ROWB = 34 * 64;  // 2176 B per halo row
    __shared__ uint4 tile4[36 * ROWB / 16];
    char* tile = (char*)tile4;

    const int No = Zo * Yo * Xo;
    const int bid = xcd_swz(blockIdx.x, gridDim.x);
    int tx = bid % nx; int tt = bid / nx; int ty = tt % ny; int tz = tt / ny;
    const int z0 = tz * 4, y0 = ty * 4, x0 = tx * 32;

    const int tid = threadIdx.x;
    const int w = tid >> 6, lane = tid & 63, lg = lane >> 4, lr = lane & 15;

    // block-wide mask ballot (one output voxel per thread)
    int anywork;
    {
        int row = tid >> 5, xl = tid & 31;
        int zz = z0 + (row >> 2), yy = y0 + (row & 3), xx = x0 + xl;
        int ok = (zz < Zo) && (yy < Yo) && (xx < Xo) && mask[((size_t)zz * Yo + yy) * Xo + xx];
        anywork = __syncthreads_or(ok);
    }

    f32x4 acc[4][2];
#pragma unroll
    for (int s = 0; s < 4; ++s) { acc[s][0] = (f32x4){0,0,0,0}; acc[s][1] = (f32x4){0,0,0,0}; }

    if (anywork) {
        // ---- stage halo: 36 rows of 2176 B ----
        for (int rr = w; rr < 36; rr += 8) {
            int dz = rr / 6, dy = rr % 6;
            const bf16* g = in + ((size_t)(z0 + dz) * Ypi + (y0 + dy)) * Xpi * 32 + (size_t)x0 * 32;
            char* l = tile + rr * ROWB;
            glds16(g + lane * 8, l);
            glds16(g + 512 + lane * 8, l + 1024);
            if (lane < 8) glds16(g + 1024 + lane * 8, l + 2048);
        }
        asm volatile("s_waitcnt vmcnt(0)" ::: "memory");
        __syncthreads();

        // per-fragment LDS base: voxel row 2w+(s>>1), x = (s&1)*16 + lr, ch grp lg
        int base_s[4];
#pragma unroll
        for (int s = 0; s < 4; ++s) {
            int lrow = 2 * w + (s >> 1);
            int zs = lrow >> 2, ys = lrow & 3;
            base_s[s] = (zs * 6 + ys) * ROWB + ((s & 1) * 16 + lr) * 64 + lg * 16;
        }

        const uint4* gw = (const uint4*)wfrag;
#pragma unroll 1
        for (int dz = 0; dz < 3; ++dz) {
#pragma unroll
            for (int dy = 0; dy < 3; ++dy) {
#pragma unroll
                for (int dx = 0; dx < 3; ++dx) {
                    const int tap = dz * 9 + dy * 3 + dx;
                    uint4 b0 = gw[(tap * 2 + 0) * 64 + lane];
                    uint4 b1 = gw[(tap * 2 + 1) * 64 + lane];
                    const int doff = (dz * 6 + dy) * ROWB + dx * 64;
                    uint4 ua[4];
#pragma unroll
                    for (int s = 0; s < 4; ++s)
                        ua[s] = *(const uint4*)(tile + base_s[s] + doff);
#pragma unroll
                    for (int s = 0; s < 4; ++s) {
                        acc[s][0] = __builtin_amdgcn_mfma_f32_16x16x32_bf16(
                            __builtin_bit_cast(s16x8, ua[s]),
                            __builtin_bit_cast(s16x8, b0), acc[s][0], 0, 0, 0);
                        acc[s][1] = __builtin_amdgcn_mfma_f32_16x16x32_bf16(
                            __builtin_bit_cast(s16x8, ua[s]),
                            __builtin_bit_cast(s16x8, b1), acc[s][1], 0, 0, 0);
                    }
                }
            }
        }
    }

    // ---- epilogue: C row = lg*4+r (voxel within fragment), col = lr (cout) ----
#pragma unroll
    for (int s = 0; s < 4; ++s) {
        int lrow = 2 * w + (s >> 1);
        int zz = z0 + (lrow >> 2), yy = y0 + (lrow & 3);
        int xv = x0 + (s & 1) * 16 + lg * 4;
        bool rowok = (zz < Zo) && (yy < Yo);
        if (!rowok) continue;
        size_t idx0 = ((size_t)zz * Yo + yy) * Xo + xv;
        float mm[4];
#pragma unroll
        for (int r = 0; r < 4; ++r)
            mm[r] = (xv + r < Xo && mask[idx0 + r]) ? 1.f : 0.f;
        if constexpr (FINAL) {
#pragma unroll
            for (int nt = 0; nt < 2; ++nt) {
                int co = nt * 16 + lr;
                float sc = scale[co], sh = shift[co];
                f32x4 o;
#pragma unroll
                for (int r = 0; r < 4; ++r)
                    o[r] = fmaxf(fmaf(acc[s][nt][r], sc, sh), 0.f) * mm[r];
                if (xv + 3 < Xo) {
                    *(f32x4*)(outf + (size_t)co * No + idx0) = o;
                } else {
#pragma unroll
                    for (int r = 0; r < 4; ++r)
                        if (xv + r < Xo) outf[(size_t)co * No + idx0 + r] = o[r];
                }
            }
        } else {
            int opd = ((zz + 1) * Ypo + (yy + 1)) * Xpo + (xv + 1);
#pragma unroll
            for (int nt = 0; nt < 2; ++nt) {
                int co = nt * 16 + lr;
                float sc = scale[co], sh = shift[co];
#pragma unroll
                for (int r = 0; r < 4; ++r) {
                    if (xv + r >= Xo) continue;
                    float yv = fmaxf(fmaf(acc[s][nt][r], sc, sh), 0.f) * mm[r];
                    out[(size_t)(opd + r) * 32 + co] = __float2bfloat16(yv);
                }
            }
        }
    }
}

// global-load MFMA conv (kept for 64ch L3b)
template <int CIN, int COUT, bool FINAL>
__global__ __launch_bounds__(256, (CIN <= 32 ? 4 : 2)) void conv_mfma_k(
    const bf16* __restrict__ in, const bf16* __restrict__ wfrag,
    const float* __restrict__ scale, const float* __restrict__ shift,
    const uint8_t* __restrict__ mask, bf16* __restrict__ out, float* __restrict__ outf,
    int Zo, int Yo, int Xo, int Ypi, int Xpi, int Ypo, int Xpo) {
    constexpr int NT = COUT / 16;
    constexpr int KT = CIN / 32;
    const int No = Zo * Yo * Xo;
    const int bid = xcd_swz(blockIdx.x, gridDim.x);
    const int tid = threadIdx.x;
    const int wv = tid >> 6, lane = tid & 63;
    const int lg = lane >> 4, lr = lane & 15;
    const int v0 = bid * 256 + wv * 64;
    if (v0 >= No) return;

    int vm = v0 + lane;
    bool mw = (vm < No) && (mask[vm] != 0);
    const bool anywork = (__ballot(mw) != 0ull);

    f32x4 acc[4][NT];
#pragma unroll
    for (int s = 0; s < 4; ++s)
#pragma unroll
        for (int nt = 0; nt < NT; ++nt) acc[s][nt] = (f32x4){0.f, 0.f, 0.f, 0.f};

    const uint4* gw = (const uint4*)wfrag;

    if (anywork) {
        int pA[4];
#pragma unroll
        for (int s = 0; s < 4; ++s) {
            int vr = v0 + s * 16 + lr;
            if (vr >= No) vr = 0;
            int zz = vr / (Yo * Xo); int rr = vr - zz * (Yo * Xo);
            int yy = rr / Xo; int xx = rr - yy * Xo;
            pA[s] = (((zz + 1) * Ypi + (yy + 1)) * Xpi + (xx + 1)) * CIN + lg * 8;
        }
#pragma unroll
        for (int tap = 0; tap < 27; ++tap) {
            const int kz = tap / 9, r9 = tap - kz * 9, ky = r9 / 3, kx = r9 - ky * 3;
            const int toff = (((kz - 1) * Ypi + (ky - 1)) * Xpi + (kx - 1)) * CIN;
            uint4 ub[NT][KT];
#pragma unroll
            for (int nt = 0; nt < NT; ++nt)
#pragma unroll
                for (int kt = 0; kt < KT; ++kt)
                    ub[nt][kt] = gw[((tap * NT + nt) * KT + kt) * 64 + lane];
            uint4 ua[4][KT];
#pragma unroll
            for (int s = 0; s < 4; ++s)
#pragma unroll
                for (int kt = 0; kt < KT; ++kt)
                    ua[s][kt] = *(const uint4*)(in + pA[s] + toff + kt * 32);
#pragma unroll
            for (int s = 0; s < 4; ++s)
#pragma unroll
                for (int kt = 0; kt < KT; ++kt)
#pragma unroll
                    for (int nt = 0; nt < NT; ++nt)
                        acc[s][nt] = __builtin_amdgcn_mfma_f32_16x16x32_bf16(
                            __builtin_bit_cast(s16x8, ua[s][kt]),
                            __builtin_bit_cast(s16x8, ub[nt][kt]), acc[s][nt], 0, 0, 0);
        }
    }

#pragma unroll
    for (int s = 0; s < 4; ++s) {
        const int vb = v0 + s * 16 + lg * 4;
        int opd[4]; float mm[4]; bool ok[4];
#pragma unroll
        for (int r = 0; r < 4; ++r) {
            int v = vb + r;
            ok[r] = v < No;
            int vc = ok[r] ? v : 0;
            mm[r] = (ok[r] && mask[vc]) ? 1.f : 0.f;
            int zz = vc / (Yo * Xo); int rr = vc - zz * (Yo * Xo);
            int yy = rr / Xo; int xx = rr - yy * Xo;
            opd[r] = ((zz + 1) * Ypo + (yy + 1)) * Xpo + (xx + 1);
        }
#pragma unroll
        for (int nt = 0; nt < NT; ++nt) {
            int co = nt * 16 + lr;
            float sc = scale[co], sh = shift[co];
#pragma unroll
            for (int r = 0; r < 4; ++r) {
                if (!ok[r]) continue;
                float yv = fmaxf(fmaf(acc[s][nt][r], sc, sh), 0.f) * mm[r];
                out[(size_t)opd[r] * COUT + co] = __float2bfloat16(yv);
            }
        }
    }
}

// MFMA transposed conv (stride 2) via parity octants; blockIdx.y = octant
template <int CIN, int COUT>
__global__ __launch_bounds__(256, 4) void tconv_mfma_k(
    const bf16* __restrict__ in, const bf16* __restrict__ wfrag,
    const float* __restrict__ scale, const float* __restrict__ shift,
    const uint8_t* __restrict__ mask, bf16* __restrict__ out,
    int Zo, int Yo, int Xo, int Ypi, int Xpi, int Ypo, int Xpo) {
    constexpr int NT = COUT / 16;
    constexpr int KT = CIN / 32;
    const int oct = blockIdx.y;
    const int pz = oct >> 2, py = (oct >> 1) & 1, px = oct & 1;
    const int Zq = (Zo - pz + 1) >> 1, Yq = (Yo - py + 1) >> 1, Xq = (Xo - px + 1) >> 1;
    const int Nq = Zq * Yq * Xq;
    const int YXq = Yq * Xq;
    const int bid = xcd_swz(blockIdx.x, gridDim.x);
    const int tid = threadIdx.x;
    const int wv = tid >> 6, lane = tid & 63;
    const int lg = lane >> 4, lr = lane & 15;
    const int v0 = bid * 256 + wv * 64;
    if (v0 >= Nq) return;

    bool mw = false;
    {
        int q = v0 + lane;
        if (q < Nq) {
            int zq = q / YXq; int rr = q - zq * YXq; int yq = rr / Xq; int xq = rr - yq * Xq;
            int zz = 2 * zq + pz, yy = 2 * yq + py, xx = 2 * xq + px;
            mw = mask[(zz * Yo + yy) * Xo + xx] != 0;
        }
    }
    const bool anywork = (__ballot(mw) != 0ull);

    f32x4 acc[4][NT];
#pragma unroll
    for (int s = 0; s < 4; ++s)
#pragma unroll
        for (int nt = 0; nt < NT; ++nt) acc[s][nt] = (f32x4){0.f, 0.f, 0.f, 0.f};

    const uint4* gw = (const uint4*)wfrag;

    if (anywork) {
        int pA[4];
#pragma unroll
        for (int s = 0; s < 4; ++s) {
            int q = v0 + s * 16 + lr;
            if (q >= Nq) q = 0;
            int zq = q / YXq; int rr = q - zq * YXq; int yq = rr / Xq; int xq = rr - yq * Xq;
            pA[s] = (((zq + 1) * Ypi + (yq + 1)) * Xpi + (xq + 1)) * CIN + lg * 8;
        }
        const int nkz = 1 + pz, nky = 1 + py, nkx = 1 + px;
        for (int iz = 0; iz < nkz; ++iz) {
            const int kz = pz ? (iz ? 2 : 0) : 1;
            const int dz = (pz && !iz) ? 1 : 0;
            for (int iy = 0; iy < nky; ++iy) {
                const int ky = py ? (iy ? 2 : 0) : 1;
                const int dy = (py && !iy) ? 1 : 0;
                for (int ix = 0; ix < nkx; ++ix) {
                    const int kx = px ? (ix ? 2 : 0) : 1;
                    const int dx = (px && !ix) ? 1 : 0;
                    const int tap = kz * 9 + ky * 3 + kx;
                    const int toff = ((dz * Ypi + dy) * Xpi + dx) * CIN;
                    uint4 ub[NT][KT];
#pragma unroll
                    for (int nt = 0; nt < NT; ++nt)
#pragma unroll
                        for (int kt = 0; kt < KT; ++kt)
                            ub[nt][kt] = gw[((tap * NT + nt) * KT + kt) * 64 + lane];
                    uint4 ua[4][KT];
#pragma unroll
                    for (int s = 0; s < 4; ++s)
#pragma unroll
                        for (int kt = 0; kt < KT; ++kt)
                            ua[s][kt] = *(const uint4*)(in + pA[s] + toff + kt * 32);
#pragma unroll
                    for (int s = 0; s < 4; ++s)
#pragma unroll
                        for (int kt = 0; kt < KT; ++kt)
#pragma unroll
                            for (int nt = 0; nt < NT; ++nt)
                                acc[s][nt] = __builtin_amdgcn_mfma_f32_16x16x32_bf16(
                                    __builtin_bit_cast(s16x8, ua[s][kt]),
                                    __builtin_bit_cast(s16x8, ub[nt][kt]), acc[s][nt], 0, 0, 0);
                }
            }
        }
    }

#pragma unroll
    for (int s = 0; s < 4; ++s) {
        const int vb = v0 + s * 16 + lg * 4;
        int opd[4]; float mm[4]; bool ok[4];
#pragma unroll
        for (int r = 0; r < 4; ++r) {
            int q = vb + r;
            ok[r] = q < Nq;
            int qc = ok[r] ? q : 0;
            int zq = qc / YXq; int rr = qc - zq * YXq; int yq = rr / Xq; int xq = rr - yq * Xq;
            int zz = 2 * zq + pz, yy = 2 * yq + py, xx = 2 * xq + px;
            mm[r] = (ok[r] && mask[(zz * Yo + yy) * Xo + xx]) ? 1.f : 0.f;
            opd[r] = ((zz + 1) * Ypo + (yy + 1)) * Xpo + (xx + 1);
        }
#pragma unroll
        for (int nt = 0; nt < NT; ++nt) {
            int co = nt * 16 + lr;
            float sc = scale[co], sh = shift[co];
#pragma unroll
            for (int r = 0; r < 4; ++r) {
                if (!ok[r]) continue;
                float yv = fmaxf(fmaf(acc[s][nt][r], sc, sh), 0.f) * mm[r];
                out[(size_t)opd[r] * COUT + co] = __float2bfloat16(yv);
            }
        }
    }
}

__global__ __launch_bounds__(256, 4) void conv_l1_mfma_k(
    const bf16* __restrict__ in, const bf16* __restrict__ wfrag,
    const float* __restrict__ scale, const float* __restrict__ shift,
    const uint8_t* __restrict__ mask, bf16* __restrict__ out,
    int Zo, int Yo, int Xo, int Ypi, int Xpi, int Ypo, int Xpo) {
    const int No = Zo * Yo * Xo;
    const int bid = xcd_swz(blockIdx.x, gridDim.x);
    const int tid = threadIdx.x;
    const int wv = tid >> 6, lane = tid & 63;
    const int lg = lane >> 4, lr = lane & 15;
    const int v0 = bid * 256 + wv * 64;
    if (v0 >= No) return;

    int vm = v0 + lane;
    bool mw = (vm < No) && (mask[vm] != 0);
    const bool anywork = (__ballot(mw) != 0ull);

    f32x4 acc[4];
#pragma unroll
    for (int s = 0; s < 4; ++s) acc[s] = (f32x4){0.f, 0.f, 0.f, 0.f};

    if (anywork) {
        const uint4* gw = (const uint4*)wfrag;
        uint4 bu[4];
#pragma unroll
        for (int kb = 0; kb < 4; ++kb) bu[kb] = gw[kb * 64 + lane];

        int vtf[4][2];
#pragma unroll
        for (int kb = 0; kb < 4; ++kb)
#pragma unroll
            for (int u = 0; u < 2; ++u) {
                int tp = kb * 8 + lg * 2 + u;
                int kz = tp / 9, r9 = tp - kz * 9, ky = r9 / 3, kx = r9 - ky * 3;
                vtf[kb][u] = (tp < 27) ? (((kz - 1) * Ypi + (ky - 1)) * Xpi + (kx - 1)) : 0;
            }

        int pV[4];
#pragma unroll
        for (int s = 0; s < 4; ++s) {
            int vr = v0 + s * 16 + lr;
            if (vr >= No) vr = 0;
            int zz = vr / (Yo * Xo); int rr = vr - zz * (Yo * Xo);
            int yy = rr / Xo; int xx = rr - yy * Xo;
            pV[s] = ((zz + 1) * Ypi + (yy + 1)) * Xpi + (xx + 1);
        }

#pragma unroll
        for (int kb = 0; kb < 4; ++kb) {
#pragma unroll
            for (int s = 0; s < 4; ++s) {
                uint2 a0 = *(const uint2*)(in + (size_t)(pV[s] + vtf[kb][0]) * 4);
                uint2 a1 = *(const uint2*)(in + (size_t)(pV[s] + vtf[kb][1]) * 4);
                int4 ai; ai.x = a0.x; ai.y = a0.y; ai.z = a1.x; ai.w = a1.y;
                acc[s] = __builtin_amdgcn_mfma_f32_16x16x32_bf16(
                    __builtin_bit_cast(s16x8, ai),
                    __builtin_bit_cast(s16x8, bu[kb]), acc[s], 0, 0, 0);
            }
        }
    }

#pragma unroll
    for (int s = 0; s < 4; ++s) {
        const int vb = v0 + s * 16 + lg * 4;
        int co = lr;
        float sc = scale[co], sh = shift[co];
#pragma unroll
        for (int r = 0; r < 4; ++r) {
            int v = vb + r;
            if (v >= No) continue;
            float mm = mask[v] ? 1.f : 0.f;
            int zz = v / (Yo * Xo); int rr = v - zz * (Yo * Xo);
            int yy = rr / Xo; int xx = rr - yy * Xo;
            int opd = ((zz + 1) * Ypo + (yy + 1)) * Xpo + (xx + 1);
            float yv = fmaxf(fmaf(acc[s][r], sc, sh), 0.f) * mm;
            out[(size_t)opd * 16 + co] = __float2bfloat16(yv);
        }
    }
}

inline int nblk(int n) { return (n + 255) / 256; }
inline int cdiv(int a, int b) { return (a + b - 1) / b; }

}  // namespace

extern "C" void kernel_launch(void* const* d_in, const int* in_sizes, int n_in,
                              void* d_out, int out_size, void* d_ws, size_t ws_size,
                              hipStream_t stream) {
    const float* feats = (const float*)d_in[0];
    const int* coords = (const int*)d_in[1];
    const int NVOX = in_sizes[0] / 4;

    const float *w1 = (const float*)d_in[3], *s1 = (const float*)d_in[4], *b1 = (const float*)d_in[5];
    const float *w2a = (const float*)d_in[6], *s2a = (const float*)d_in[7], *b2a = (const float*)d_in[8];
    const float *w2b = (const float*)d_in[9], *s2b = (const float*)d_in[10], *b2b = (const float*)d_in[11];
    const float *w3a = (const float*)d_in[12], *s3a = (const float*)d_in[13], *b3a = (const float*)d_in[14];
    const float *w3b = (const float*)d_in[15], *s3b = (const float*)d_in[16], *b3b = (const float*)d_in[17];
    const float *w4a = (const float*)d_in[18], *s4a = (const float*)d_in[19], *b4a = (const float*)d_in[20];
    const float *w4b = (const float*)d_in[21], *s4b = (const float*)d_in[22], *b4b = (const float*)d_in[23];
    const float *w5a = (const float*)d_in[24], *s5a = (const float*)d_in[25], *b5a = (const float*)d_in[26];
    const float *w5b = (const float*)d_in[27], *s5b = (const float*)d_in[28], *b5b = (const float*)d_in[29];

    char* ws = (char*)d_ws;
    size_t off = 0;
    auto alloc = [&](size_t bytes) -> void* {
        void* p = ws + off;
        off = (off + bytes + 255) & ~(size_t)255;
        return p;
    };

    uint8_t* m0 = (uint8_t*)alloc(NV0);
    uint8_t* m1 = (uint8_t*)alloc(NV0);
    uint8_t* m2 = (uint8_t*)alloc(NV2);
    uint8_t* m3 = (uint8_t*)alloc(NV3);
    uint8_t* m4 = (uint8_t*)alloc(NV4);
    uint8_t* m5 = (uint8_t*)alloc(NV0);

    bf16* slot0 = (bf16*)alloc((size_t)NP0 * 32 * 2);
    bf16* slot1 = (bf16*)alloc((size_t)NP0 * 16 * 2);

    bf16* dense0 = slot0;  // 4ch  @P0
    bf16* x1     = slot1;  // 16ch @P0
    bf16* x2a    = slot0;  // 32ch @P2
    bf16* x2b    = slot1;  // 32ch @P2
    bf16* x3a    = slot0;  // 64ch @P3
    bf16* x3b    = slot1;  // 64ch @P3
    bf16* x4a    = slot0;  // 32ch @P4
    bf16* x4b    = slot1;  // 32ch @(23,130,130)
    bf16* x5a    = slot0;  // 32ch @P0

    float* w2aT = (float*)alloc(27 * 16 * 32 * 4);
    float* w3aT = (float*)alloc(27 * 32 * 64 * 4);
    bf16* wfL1 = (bf16*)alloc(4 * 64 * 8 * 2);
    bf16* wf2b = (bf16*)alloc((size_t)27 * 2 * 1 * 64 * 16);
    bf16* wf3b = (bf16*)alloc((size_t)27 * 4 * 2 * 64 * 16);
    bf16* wf4a = (bf16*)alloc((size_t)27 * 2 * 2 * 64 * 16);
    bf16* wf4b = (bf16*)alloc((size_t)27 * 2 * 1 * 64 * 16);
    bf16* wf5a = (bf16*)alloc((size_t)27 * 2 * 1 * 64 * 16);
    bf16* wf5b = (bf16*)alloc((size_t)27 * 2 * 1 * 64 * 16);
    alloc(20u << 20);  // slack for OOB halo reads of partial tiles

    if (off > ws_size) {
        sentinel_k<<<1, 256, 0, stream>>>((float*)d_out);
        return;
    }

    // stage 0
    hipMemsetAsync(dense0, 0, (size_t)NP0 * 4 * 2, stream);
    hipMemsetAsync(m0, 0, NV0, stream);
    repack_valu_conv_k<<<nblk(27 * 16 * 32), 256, 0, stream>>>(w2a, w2aT, 16, 32);
    repack_valu_conv_k<<<nblk(27 * 32 * 64), 256, 0, stream>>>(w3a, w3aT, 32, 64);
    repack_frag_l1_k<<<1, 256, 0, stream>>>(w1, wfL1);
    repack_frag_k<<<nblk(27 * 2 * 64), 256, 0, stream>>>(w2b, wf2b, 32, 32, 0);
    repack_frag_k<<<nblk(27 * 8 * 64), 256, 0, stream>>>(w3b, wf3b, 64, 64, 0);
    repack_frag_k<<<nblk(27 * 4 * 64), 256, 0, stream>>>(w4a, wf4a, 64, 32, 1);
    repack_frag_k<<<nblk(27 * 2 * 64), 256, 0, stream>>>(w4b, wf4b, 32, 32, 0);
    repack_frag_k<<<nblk(27 * 2 * 64), 256, 0, stream>>>(w5a, wf5a, 32, 32, 1);
    repack_frag_k<<<nblk(27 * 2 * 64), 256, 0, stream>>>(w5b, wf5b, 32, 32, 0);

    scatter_k<<<nblk(NVOX), 256, 0, stream>>>(feats, coords, dense0, m0, NVOX);

    // level 1
    dilate4_k<<<nblk(NV0 / 4), 256, 0, stream>>>(m0, m1, Z0, Y0, X0);
    halo_zero_k<16><<<nblk(NP0), 256, 0, stream>>>(x1, Z0, Y0, X0, ZP0, YP0, XP0);
    conv_l1_mfma_k<<<nblk(NV0), 256, 0, stream>>>(
        dense0, wfL1, s1, b1, m1, x1, Z0, Y0, X0, YP0, XP0, YP0, XP0);

    // level 2
    dilate_k<<<nblk(NV2), 256, 0, stream>>>(m1, m2, Z0, Y0, X0, Z2, Y2, X2, 2);
    halo_zero_k<32><<<nblk(NP2), 256, 0, stream>>>(x2a, Z2, Y2, X2, ZP2, YP2, XP2);
    conv_valu_k<16, 32, 2><<<nblk(NV2), 256, 0, stream>>>(
        x1, w2aT, s2a, b2a, m2, x2a, Z2, Y2, X2, YP0, XP0, YP2, XP2);
    halo_zero_k<32><<<nblk(NP2), 256, 0, stream>>>(x2b, Z2, Y2, X2, ZP2, YP2, XP2);
    {
        int nx = cdiv(X2, 32), ny = cdiv(Y2, 4), nz = cdiv(Z2, 4);
        conv_lds_k<false><<<nx * ny * nz, 512, 0, stream>>>(
            x2a, wf2b, s2b, b2b, m2, x2b, nullptr, Z2, Y2, X2, YP2, XP2, YP2, XP2, nx, ny);
    }

    // level 3
    dilate_k<<<nblk(NV3), 256, 0, stream>>>(m2, m3, Z2, Y2, X2, Z3, Y3, X3, 2);
    halo_zero_k<64><<<nblk(NP3), 256, 0, stream>>>(x3a, Z3, Y3, X3, ZP3, YP3, XP3);
    conv_valu_k<32, 64, 2><<<nblk(NV3), 256, 0, stream>>>(
        x2b, w3aT, s3a, b3a, m3, x3a, Z3, Y3, X3, YP2, XP2, YP3, XP3);
    halo_zero_k<64><<<nblk(NP3), 256, 0, stream>>>(x3b, Z3, Y3, X3, ZP3, YP3, XP3);
    conv_mfma_k<64, 64, false><<<nblk(NV3), 256, 0, stream>>>(
        x3a, wf3b, s3b, b3b, m3, x3b, nullptr, Z3, Y3, X3, YP3, XP3, YP3, XP3);

    // level 4 (tconv up via parity octants)
    tdilate_k<<<nblk(NV4), 256, 0, stream>>>(m3, m4, Z3, Y3, X3, Z4, Y4, X4);
    halo_zero_k<32><<<nblk(NP4), 256, 0, stream>>>(x4a, Z4, Y4, X4, ZP4, YP4, XP4);
    {
        int maxNq = ((Z4 + 1) >> 1) * ((Y4 + 1) >> 1) * ((X4 + 1) >> 1);
        dim3 g(nblk(maxNq), 8);
        tconv_mfma_k<64, 32><<<g, 256, 0, stream>>>(
            x3b, wf4a, s4a, b4a, m4, x4a, Z4, Y4, X4, YP3, XP3, YP4, XP4);
    }
    halo_zero_k<32><<<nblk(NP2), 256, 0, stream>>>(x4b, Z4, Y4, X4, ZP2, YP2, XP2);
    {
        int nx = cdiv(X4, 32), ny = cdiv(Y4, 4), nz = cdiv(Z4, 4);
        conv_lds_k<false><<<nx * ny * nz, 512, 0, stream>>>(
            x4a, wf4b, s4b, b4b, m4, x4b, nullptr, Z4, Y4, X4, YP4, XP4, YP2, XP2, nx, ny);
    }

    // level 5 (tconv up, outpad (0,3,3))
    tdilate_k<<<nblk(NV0), 256, 0, stream>>>(m4, m5, Z4, Y4, X4, Z0, Y0, X0);
    halo_zero_k<32><<<nblk(NP0), 256, 0, stream>>>(x5a, Z0, Y0, X0, ZP0, YP0, XP0);
    {
        int maxNq = ((Z0 + 1) >> 1) * (Y0 >> 1) * (X0 >> 1);
        dim3 g(nblk(maxNq), 8);
        tconv_mfma_k<32, 32><<<g, 256, 0, stream>>>(
            x4b, wf5a, s5a, b5a, m5, x5a, Z0, Y0, X0, YP2, XP2, YP0, XP0);
    }
    {
        int nx = cdiv(X0, 32), ny = cdiv(Y0, 4), nz = cdiv(Z0, 4);
        conv_lds_k<true><<<nx * ny * nz, 512, 0, stream>>>(
            x5a, wf5b, s5b, b5b, m5, nullptr, (float*)d_out, Z0, Y0, X0, YP0, XP0, 0, 0, nx, ny);
    }
}

// Round 5
// 964.183 us; speedup vs baseline: 4.0137x; 1.2593x over previous
//
#include <hip/hip_runtime.h>
#include <hip/hip_bf16.h>
#include <stdint.h>

namespace {

constexpr int Z0 = 41, Y0 = 256, X0 = 256;
constexpr int Z2 = 21, Y2 = 128, X2 = 128;
constexpr int Z3 = 11, Y3 = 64,  X3 = 64;
constexpr int Z4 = 21, Y4 = 127, X4 = 127;
constexpr int NV0 = Z0 * Y0 * X0;
constexpr int NV2 = Z2 * Y2 * X2;
constexpr int NV3 = Z3 * Y3 * X3;
constexpr int NV4 = Z4 * Y4 * X4;

constexpr int ZP0 = 43, YP0 = 258, XP0 = 258; constexpr int NP0 = ZP0 * YP0 * XP0;
constexpr int ZP2 = 23, YP2 = 130, XP2 = 130; constexpr int NP2 = ZP2 * YP2 * XP2;
constexpr int ZP3 = 13, YP3 = 66,  XP3 = 66;  constexpr int NP3 = ZP3 * YP3 * XP3;
constexpr int ZP4 = 23, YP4 = 129, XP4 = 129; constexpr int NP4 = ZP4 * YP4 * XP4;

using bf16 = __hip_bfloat16;
typedef __attribute__((ext_vector_type(8))) short s16x8;
typedef __attribute__((ext_vector_type(4))) float f32x4;

__device__ inline float bflo(unsigned u) { return __builtin_bit_cast(float, u << 16); }
__device__ inline float bfhi(unsigned u) { return __builtin_bit_cast(float, u & 0xffff0000u); }
__device__ inline unsigned f2b(float f) {
    return (unsigned)__builtin_bit_cast(unsigned short, __float2bfloat16(f));
}

__device__ inline int xcd_swz(int bid, int nwg) {
    int q = nwg >> 3, r = nwg & 7;
    int x = bid & 7, j = bid >> 3;
    return (x < r ? x * (q + 1) : r * (q + 1) + (x - r) * q) + j;
}

__device__ inline void glds16(const bf16* g, void* l) {
    __builtin_amdgcn_global_load_lds(
        (const __attribute__((address_space(1))) void*)g,
        (__attribute__((address_space(3))) void*)l, 16, 0, 0);
}

__global__ __launch_bounds__(256) void sentinel_k(float* out) { out[0] = 12345.0f; }

__global__ __launch_bounds__(256) void scatter_k(const float* __restrict__ feats,
                                                 const int* __restrict__ coords,
                                                 bf16* __restrict__ dense,
                                                 uint8_t* __restrict__ m0, int n) {
    int v = blockIdx.x * 256 + threadIdx.x;
    if (v >= n) return;
    int z = coords[v * 4 + 1], y = coords[v * 4 + 2], x = coords[v * 4 + 3];
    m0[(z * Y0 + y) * X0 + x] = 1;
    int pp = ((z + 1) * YP0 + (y + 1)) * XP0 + (x + 1);
    uint2 u;
    u.x = f2b(feats[v * 4 + 0]) | (f2b(feats[v * 4 + 1]) << 16);
    u.y = f2b(feats[v * 4 + 2]) | (f2b(feats[v * 4 + 3]) << 16);
    *(uint2*)(dense + (size_t)pp * 4) = u;
}

template <int C>
__global__ __launch_bounds__(256) void halo_zero_k(bf16* __restrict__ buf,
                                                   int Zi, int Yi, int Xi,
                                                   int Zp, int Yp, int Xp) {
    int i = blockIdx.x * 256 + threadIdx.x;
    int tot = Zp * Yp * Xp;
    if (i >= tot) return;
    int x = i % Xp; int t = i / Xp; int y = t % Yp; int z = t / Yp;
    bool halo = (z < 1) | (z > Zi) | (y < 1) | (y > Yi) | (x < 1) | (x > Xi);
    if (!halo) return;
    uint4 zz = make_uint4(0, 0, 0, 0);
    uint4* p = (uint4*)(buf + (size_t)i * C);
#pragma unroll
    for (int j = 0; j < C / 8; ++j) p[j] = zz;
}

__global__ __launch_bounds__(256) void repack_frag_k(const float* __restrict__ w,
                                                     bf16* __restrict__ wf,
                                                     int CIN, int COUT, int TRANS) {
    int NT = COUT / 16, KT = CIN / 32;
    int i = blockIdx.x * 256 + threadIdx.x;
    int total = 27 * NT * KT * 64;
    if (i >= total) return;
    int lane = i & 63; int t = i >> 6;
    int kt = t % KT; t /= KT; int nt = t % NT; int tap = t / NT;
    int co = nt * 16 + (lane & 15);
    int ci0 = kt * 32 + (lane >> 4) * 8;
    unsigned e[8];
#pragma unroll
    for (int j = 0; j < 8; ++j) {
        int ci = ci0 + j;
        int src = TRANS ? ((ci * COUT + co) * 27 + tap) : ((co * CIN + ci) * 27 + tap);
        e[j] = f2b(w[src]);
    }
    uint4 u;
    u.x = e[0] | (e[1] << 16); u.y = e[2] | (e[3] << 16);
    u.z = e[4] | (e[5] << 16); u.w = e[6] | (e[7] << 16);
    ((uint4*)wf)[i] = u;
}

// CIN=16 stride-2 frag: K = 2 taps x 16ch, 14 pairs (tap 27 zero)
__global__ __launch_bounds__(256) void repack_frag_c16_k(const float* __restrict__ w,
                                                         bf16* __restrict__ wf) {
    int i = blockIdx.x * 256 + threadIdx.x;
    int total = 14 * 2 * 64;
    if (i >= total) return;
    int lane = i & 63; int t = i >> 6;
    int nt = t & 1; int p = t >> 1;
    int lg = lane >> 4, lr = lane & 15;
    int co = nt * 16 + lr;
    unsigned e[8];
#pragma unroll
    for (int j = 0; j < 8; ++j) {
        int tap = 2 * p + (lg >> 1);
        int ci = (lg & 1) * 8 + j;
        e[j] = (tap < 27) ? f2b(w[(co * 16 + ci) * 27 + tap]) : 0u;
    }
    uint4 u;
    u.x = e[0] | (e[1] << 16); u.y = e[2] | (e[3] << 16);
    u.z = e[4] | (e[5] << 16); u.w = e[6] | (e[7] << 16);
    ((uint4*)wf)[i] = u;
}

__global__ __launch_bounds__(256) void repack_frag_l1_k(const float* __restrict__ w,
                                                        bf16* __restrict__ wf) {
    int i = blockIdx.x * 256 + threadIdx.x;
    if (i >= 256) return;
    int lane = i & 63, kb = i >> 6;
    int lg = lane >> 4, lr = lane & 15;
    unsigned e[8];
#pragma unroll
    for (int j = 0; j < 8; ++j) {
        int tap = kb * 8 + lg * 2 + (j >> 2);
        int ci = j & 3;
        e[j] = (tap < 27) ? f2b(w[(lr * 4 + ci) * 27 + tap]) : 0u;
    }
    uint4 u;
    u.x = e[0] | (e[1] << 16); u.y = e[2] | (e[3] << 16);
    u.z = e[4] | (e[5] << 16); u.w = e[6] | (e[7] << 16);
    ((uint4*)wf)[i] = u;
}

__global__ __launch_bounds__(256) void dilate_k(const uint8_t* __restrict__ in,
                                                uint8_t* __restrict__ out,
                                                int Zi, int Yi, int Xi,
                                                int Zo, int Yo, int Xo, int stride) {
    int idx = blockIdx.x * 256 + threadIdx.x;
    int total = Zo * Yo * Xo;
    if (idx >= total) return;
    int x = idx % Xo; int t = idx / Xo; int y = t % Yo; int z = t / Yo;
    int YX = Yi * Xi;
    uint8_t r = 0;
    for (int kz = 0; kz < 3; ++kz) {
        int zi = z * stride + kz - 1;
        if ((unsigned)zi >= (unsigned)Zi) continue;
        for (int ky = 0; ky < 3; ++ky) {
            int yi = y * stride + ky - 1;
            if ((unsigned)yi >= (unsigned)Yi) continue;
            for (int kx = 0; kx < 3; ++kx) {
                int xi = x * stride + kx - 1;
                if ((unsigned)xi >= (unsigned)Xi) continue;
                r |= in[zi * YX + yi * Xi + xi];
            }
        }
    }
    out[idx] = r ? 1 : 0;
}

__global__ __launch_bounds__(256) void dilate4_k(const uint8_t* __restrict__ in,
                                                 uint8_t* __restrict__ out,
                                                 int Z, int Y, int X) {
    int ngx = X >> 2;
    int g = blockIdx.x * 256 + threadIdx.x;
    int total = Z * Y * ngx;
    if (g >= total) return;
    int gx = g % ngx; int t = g / ngx; int y = t % Y; int z = t / Y;
    const int YX = Y * X;
    unsigned r = 0;
    for (int kz = 0; kz < 3; ++kz) {
        int zi = z + kz - 1;
        if ((unsigned)zi >= (unsigned)Z) continue;
        for (int ky = 0; ky < 3; ++ky) {
            int yi = y + ky - 1;
            if ((unsigned)yi >= (unsigned)Y) continue;
            const unsigned* rw = (const unsigned*)(in + zi * YX + yi * X);
            unsigned u1 = rw[gx];
            unsigned u0 = gx ? rw[gx - 1] : 0u;
            unsigned u2 = (gx + 1 < ngx) ? rw[gx + 1] : 0u;
            r |= u1 | ((u1 << 8) | (u0 >> 24)) | ((u1 >> 8) | (u2 << 24));
        }
    }
    r |= r >> 4; r |= r >> 2; r |= r >> 1; r &= 0x01010101u;
    ((unsigned*)out)[g] = r;
}

__global__ __launch_bounds__(256) void tdilate_k(const uint8_t* __restrict__ in,
                                                 uint8_t* __restrict__ out,
                                                 int Zi, int Yi, int Xi,
                                                 int Zo, int Yo, int Xo) {
    int idx = blockIdx.x * 256 + threadIdx.x;
    int total = Zo * Yo * Xo;
    if (idx >= total) return;
    int x = idx % Xo; int t = idx / Xo; int y = t % Yo; int z = t / Yo;
    int YX = Yi * Xi;
    uint8_t r = 0;
    for (int kz = 0; kz < 3; ++kz) {
        int tz = z + 1 - kz;
        if (tz & 1) continue;
        int zi = tz >> 1;
        if ((unsigned)zi >= (unsigned)Zi) continue;
        for (int ky = 0; ky < 3; ++ky) {
            int ty = y + 1 - ky;
            if (ty & 1) continue;
            int yi = ty >> 1;
            if ((unsigned)yi >= (unsigned)Yi) continue;
            for (int kx = 0; kx < 3; ++kx) {
                int tx = x + 1 - kx;
                if (tx & 1) continue;
                int xi = tx >> 1;
                if ((unsigned)xi >= (unsigned)Xi) continue;
                r |= in[zi * YX + yi * Xi + xi];
            }
        }
    }
    out[idx] = r ? 1 : 0;
}

// LDS-tiled MFMA stride-1 conv, CIN=COUT=32, XOR-swizzled LDS (2-way banks).
template <bool FINAL>
__global__ __launch_bounds__(512, 4) void conv_lds_k(
    const bf16* __restrict__ in, const bf16* __restrict__ wfrag,
    const float* __restrict__ scale, const float* __restrict__ shift,
    const uint8_t* __restrict__ mask, bf16* __restrict__ out, float* __restrict__ outf,
    int Zo, int Yo, int Xo, int Ypi, int Xpi, int Ypo, int Xpo, int nx, int ny) {
    constexpr int ROWB = 34 * 64;  // 2176 B per halo row (17*128 -> 128B aligned)
    __shared__ uint4 tile4[36 * ROWB / 16];
    char* tile = (char*)tile4;

    const int No = Zo * Yo * Xo;
    const int bid = xcd_swz(blockIdx.x, gridDim.x);
    int tx = bid % nx; int tt = bid / nx; int ty = tt % ny; int tz = tt / ny;
    const int z0 = tz * 4, y0 = ty * 4, x0 = tx * 32;

    const int tid = threadIdx.x;
    const int w = tid >> 6, lane = tid & 63, lg = lane >> 4, lr = lane & 15;

    int anywork;
    {
        int row = tid >> 5, xl = tid & 31;
        int zz = z0 + (row >> 2), yy = y0 + (row & 3), xx = x0 + xl;
        int ok = (zz < Zo) && (yy < Yo) && (xx < Xo) && mask[((size_t)zz * Yo + yy) * Xo + xx];
        anywork = __syncthreads_or(ok);
    }

    f32x4 acc[4][2];
#pragma unroll
    for (int s = 0; s < 4; ++s) { acc[s][0] = (f32x4){0,0,0,0}; acc[s][1] = (f32x4){0,0,0,0}; }

    if (anywork) {
        // ---- stage halo, pre-swizzled global source (inverse of read swizzle) ----
        const int lsw = (lane ^ ((lane >> 3) & 7)) * 8;  // bf16 units
        for (int rr = w; rr < 36; rr += 8) {
            int dz = rr / 6, dy = rr % 6;
            const bf16* g = in + ((size_t)(z0 + dz) * Ypi + (y0 + dy)) * Xpi * 32 + (size_t)x0 * 32;
            char* l = tile + rr * ROWB;
            glds16(g + lsw, l);
            glds16(g + 512 + lsw, l + 1024);
            if (lane < 8) glds16(g + 1024 + lane * 8, l + 2048);
        }
        asm volatile("s_waitcnt vmcnt(0)" ::: "memory");
        __syncthreads();

        // per-s: row base and swizzled x/ch byte offsets for dx=0..2
        int rbB[4], bsw[4][3];
#pragma unroll
        for (int s = 0; s < 4; ++s) {
            int lrow = 2 * w + (s >> 1);
            rbB[s] = ((lrow >> 2) * 6 + (lrow & 3)) * ROWB;
            int xpart = (s & 1) * 16 + lr;
#pragma unroll
            for (int dx = 0; dx < 3; ++dx) {
                int b = (xpart + dx) * 64 + lg * 16;
                bsw[s][dx] = b ^ (((b >> 7) & 7) << 4);
            }
        }

        const uint4* gw = (const uint4*)wfrag;
#pragma unroll 1
        for (int dz = 0; dz < 3; ++dz) {
#pragma unroll
            for (int dy = 0; dy < 3; ++dy) {
                const int rowoff = (dz * 6 + dy) * ROWB;
#pragma unroll
                for (int dx = 0; dx < 3; ++dx) {
                    const int tap = dz * 9 + dy * 3 + dx;
                    uint4 b0 = gw[(tap * 2 + 0) * 64 + lane];
                    uint4 b1 = gw[(tap * 2 + 1) * 64 + lane];
                    uint4 ua[4];
#pragma unroll
                    for (int s = 0; s < 4; ++s)
                        ua[s] = *(const uint4*)(tile + rbB[s] + rowoff + bsw[s][dx]);
#pragma unroll
                    for (int s = 0; s < 4; ++s) {
                        acc[s][0] = __builtin_amdgcn_mfma_f32_16x16x32_bf16(
                            __builtin_bit_cast(s16x8, ua[s]),
                            __builtin_bit_cast(s16x8, b0), acc[s][0], 0, 0, 0);
                        acc[s][1] = __builtin_amdgcn_mfma_f32_16x16x32_bf16(
                            __builtin_bit_cast(s16x8, ua[s]),
                            __builtin_bit_cast(s16x8, b1), acc[s][1], 0, 0, 0);
                    }
                }
            }
        }
    }

#pragma unroll
    for (int s = 0; s < 4; ++s) {
        int lrow = 2 * w + (s >> 1);
        int zz = z0 + (lrow >> 2), yy = y0 + (lrow & 3);
        int xv = x0 + (s & 1) * 16 + lg * 4;
        bool rowok = (zz < Zo) && (yy < Yo);
        if (!rowok) continue;
        size_t idx0 = ((size_t)zz * Yo + yy) * Xo + xv;
        float mm[4];
#pragma unroll
        for (int r = 0; r < 4; ++r)
            mm[r] = (xv + r < Xo && mask[idx0 + r]) ? 1.f : 0.f;
        if constexpr (FINAL) {
#pragma unroll
            for (int nt = 0; nt < 2; ++nt) {
                int co = nt * 16 + lr;
                float sc = scale[co], sh = shift[co];
                f32x4 o;
#pragma unroll
                for (int r = 0; r < 4; ++r)
                    o[r] = fmaxf(fmaf(acc[s][nt][r], sc, sh), 0.f) * mm[r];
                if (xv + 3 < Xo) {
                    *(f32x4*)(outf + (size_t)co * No + idx0) = o;
                } else {
#pragma unroll
                    for (int r = 0; r < 4; ++r)
                        if (xv + r < Xo) outf[(size_t)co * No + idx0 + r] = o[r];
                }
            }
        } else {
            int opd = ((zz + 1) * Ypo + (yy + 1)) * Xpo + (xv + 1);
#pragma unroll
            for (int nt = 0; nt < 2; ++nt) {
                int co = nt * 16 + lr;
                float sc = scale[co], sh = shift[co];
#pragma unroll
                for (int r = 0; r < 4; ++r) {
                    if (xv + r >= Xo) continue;
                    float yv = fmaxf(fmaf(acc[s][nt][r], sc, sh), 0.f) * mm[r];
                    out[(size_t)(opd + r) * 32 + co] = __float2bfloat16(yv);
                }
            }
        }
    }
}

// global-load MFMA conv, generic stride & block size
template <int CIN, int COUT, int STRIDE, int BLK, bool FINAL>
__global__ __launch_bounds__(BLK, ((CIN <= 32 && COUT <= 32) ? 4 : 2)) void conv_mfma_k(
    const bf16* __restrict__ in, const bf16* __restrict__ wfrag,
    const float* __restrict__ scale, const float* __restrict__ shift,
    const uint8_t* __restrict__ mask, bf16* __restrict__ out, float* __restrict__ outf,
    int Zo, int Yo, int Xo, int Ypi, int Xpi, int Ypo, int Xpo) {
    constexpr int NT = COUT / 16;
    constexpr int KT = CIN / 32;
    const int No = Zo * Yo * Xo;
    const int bid = xcd_swz(blockIdx.x, gridDim.x);
    const int tid = threadIdx.x;
    const int wv = tid >> 6, lane = tid & 63;
    const int lg = lane >> 4, lr = lane & 15;
    const int v0 = bid * BLK + wv * 64;
    if (v0 >= No) return;

    int vm = v0 + lane;
    bool mw = (vm < No) && (mask[vm] != 0);
    const bool anywork = (__ballot(mw) != 0ull);

    f32x4 acc[4][NT];
#pragma unroll
    for (int s = 0; s < 4; ++s)
#pragma unroll
        for (int nt = 0; nt < NT; ++nt) acc[s][nt] = (f32x4){0.f, 0.f, 0.f, 0.f};

    const uint4* gw = (const uint4*)wfrag;

    if (anywork) {
        int pA[4];
#pragma unroll
        for (int s = 0; s < 4; ++s) {
            int vr = v0 + s * 16 + lr;
            if (vr >= No) vr = 0;
            int zz = vr / (Yo * Xo); int rr = vr - zz * (Yo * Xo);
            int yy = rr / Xo; int xx = rr - yy * Xo;
            pA[s] = (((zz * STRIDE + 1) * Ypi + (yy * STRIDE + 1)) * Xpi + (xx * STRIDE + 1)) * CIN + lg * 8;
        }
#pragma unroll
        for (int tap = 0; tap < 27; ++tap) {
            const int kz = tap / 9, r9 = tap - kz * 9, ky = r9 / 3, kx = r9 - ky * 3;
            const int toff = (((kz - 1) * Ypi + (ky - 1)) * Xpi + (kx - 1)) * CIN;
            uint4 ub[NT][KT];
#pragma unroll
            for (int nt = 0; nt < NT; ++nt)
#pragma unroll
                for (int kt = 0; kt < KT; ++kt)
                    ub[nt][kt] = gw[((tap * NT + nt) * KT + kt) * 64 + lane];
            uint4 ua[4][KT];
#pragma unroll
            for (int s = 0; s < 4; ++s)
#pragma unroll
                for (int kt = 0; kt < KT; ++kt)
                    ua[s][kt] = *(const uint4*)(in + pA[s] + toff + kt * 32);
#pragma unroll
            for (int s = 0; s < 4; ++s)
#pragma unroll
                for (int kt = 0; kt < KT; ++kt)
#pragma unroll
                    for (int nt = 0; nt < NT; ++nt)
                        acc[s][nt] = __builtin_amdgcn_mfma_f32_16x16x32_bf16(
                            __builtin_bit_cast(s16x8, ua[s][kt]),
                            __builtin_bit_cast(s16x8, ub[nt][kt]), acc[s][nt], 0, 0, 0);
        }
    }

#pragma unroll
    for (int s = 0; s < 4; ++s) {
        const int vb = v0 + s * 16 + lg * 4;
        int opd[4]; float mm[4]; bool ok[4];
#pragma unroll
        for (int r = 0; r < 4; ++r) {
            int v = vb + r;
            ok[r] = v < No;
            int vc = ok[r] ? v : 0;
            mm[r] = (ok[r] && mask[vc]) ? 1.f : 0.f;
            int zz = vc / (Yo * Xo); int rr = vc - zz * (Yo * Xo);
            int yy = rr / Xo; int xx = rr - yy * Xo;
            opd[r] = FINAL ? vc : ((zz + 1) * Ypo + (yy + 1)) * Xpo + (xx + 1);
        }
#pragma unroll
        for (int nt = 0; nt < NT; ++nt) {
            int co = nt * 16 + lr;
            float sc = scale[co], sh = shift[co];
#pragma unroll
            for (int r = 0; r < 4; ++r) {
                if (!ok[r]) continue;
                float yv = fmaxf(fmaf(acc[s][nt][r], sc, sh), 0.f) * mm[r];
                if constexpr (FINAL) outf[(size_t)co * No + opd[r]] = yv;
                else out[(size_t)opd[r] * COUT + co] = __float2bfloat16(yv);
            }
        }
    }
}

// stride-2 CIN=16 MFMA conv (L2a): K = 2 taps x 16 ch, 14 pairs
__global__ __launch_bounds__(256, 4) void conv_s2c16_k(
    const bf16* __restrict__ in, const bf16* __restrict__ wfrag,
    const float* __restrict__ scale, const float* __restrict__ shift,
    const uint8_t* __restrict__ mask, bf16* __restrict__ out,
    int Zo, int Yo, int Xo, int Ypi, int Xpi, int Ypo, int Xpo) {
    const int No = Zo * Yo * Xo;
    const int bid = xcd_swz(blockIdx.x, gridDim.x);
    const int tid = threadIdx.x;
    const int wv = tid >> 6, lane = tid & 63;
    const int lg = lane >> 4, lr = lane & 15;
    const int v0 = bid * 256 + wv * 64;
    if (v0 >= No) return;

    int vm = v0 + lane;
    bool mw = (vm < No) && (mask[vm] != 0);
    const bool anywork = (__ballot(mw) != 0ull);

    f32x4 acc[4][2];
#pragma unroll
    for (int s = 0; s < 4; ++s) { acc[s][0] = (f32x4){0,0,0,0}; acc[s][1] = (f32x4){0,0,0,0}; }

    if (anywork) {
        const uint4* gw = (const uint4*)wfrag;
        const int choff = (lg & 1) * 8;
        const int tb = lg >> 1;
        int toffl[14];
#pragma unroll
        for (int p = 0; p < 14; ++p) {
            int tp = 2 * p + tb;
            if (tp >= 27) tp = 0;  // dummy: B is zero, addr must be valid
            int kz = tp / 9, r9 = tp - kz * 9, ky = r9 / 3, kx = r9 - ky * 3;
            toffl[p] = ((kz * Ypi + ky) * Xpi + kx) * 16;
        }
        int pA[4];
#pragma unroll
        for (int s = 0; s < 4; ++s) {
            int vr = v0 + s * 16 + lr;
            if (vr >= No) vr = 0;
            int zz = vr / (Yo * Xo); int rr = vr - zz * (Yo * Xo);
            int yy = rr / Xo; int xx = rr - yy * Xo;
            pA[s] = (((zz * 2) * Ypi + (yy * 2)) * Xpi + (xx * 2)) * 16 + choff;
        }
#pragma unroll
        for (int p = 0; p < 14; ++p) {
            uint4 b0 = gw[(p * 2 + 0) * 64 + lane];
            uint4 b1 = gw[(p * 2 + 1) * 64 + lane];
            uint4 ua[4];
#pragma unroll
            for (int s = 0; s < 4; ++s)
                ua[s] = *(const uint4*)(in + pA[s] + toffl[p]);
#pragma unroll
            for (int s = 0; s < 4; ++s) {
                acc[s][0] = __builtin_amdgcn_mfma_f32_16x16x32_bf16(
                    __builtin_bit_cast(s16x8, ua[s]),
                    __builtin_bit_cast(s16x8, b0), acc[s][0], 0, 0, 0);
                acc[s][1] = __builtin_amdgcn_mfma_f32_16x16x32_bf16(
                    __builtin_bit_cast(s16x8, ua[s]),
                    __builtin_bit_cast(s16x8, b1), acc[s][1], 0, 0, 0);
            }
        }
    }

#pragma unroll
    for (int s = 0; s < 4; ++s) {
        const int vb = v0 + s * 16 + lg * 4;
        int opd[4]; float mm[4]; bool ok[4];
#pragma unroll
        for (int r = 0; r < 4; ++r) {
            int v = vb + r;
            ok[r] = v < No;
            int vc = ok[r] ? v : 0;
            mm[r] = (ok[r] && mask[vc]) ? 1.f : 0.f;
            int zz = vc / (Yo * Xo); int rr = vc - zz * (Yo * Xo);
            int yy = rr / Xo; int xx = rr - yy * Xo;
            opd[r] = ((zz + 1) * Ypo + (yy + 1)) * Xpo + (xx + 1);
        }
#pragma unroll
        for (int nt = 0; nt < 2; ++nt) {
            int co = nt * 16 + lr;
            float sc = scale[co], sh = shift[co];
#pragma unroll
            for (int r = 0; r < 4; ++r) {
                if (!ok[r]) continue;
                float yv = fmaxf(fmaf(acc[s][nt][r], sc, sh), 0.f) * mm[r];
                out[(size_t)opd[r] * 32 + co] = __float2bfloat16(yv);
            }
        }
    }
}

// MFMA transposed conv (stride 2) via parity octants; blockIdx.y = octant
template <int CIN, int COUT>
__global__ __launch_bounds__(256, 4) void tconv_mfma_k(
    const bf16* __restrict__ in, const bf16* __restrict__ wfrag,
    const float* __restrict__ scale, const float* __restrict__ shift,
    const uint8_t* __restrict__ mask, bf16* __restrict__ out,
    int Zo, int Yo, int Xo, int Ypi, int Xpi, int Ypo, int Xpo) {
    constexpr int NT = COUT / 16;
    constexpr int KT = CIN / 32;
    const int oct = blockIdx.y;
    const int pz = oct >> 2, py = (oct >> 1) & 1, px = oct & 1;
    const int Zq = (Zo - pz + 1) >> 1, Yq = (Yo - py + 1) >> 1, Xq = (Xo - px + 1) >> 1;
    const int Nq = Zq * Yq * Xq;
    const int YXq = Yq * Xq;
    const int bid = xcd_swz(blockIdx.x, gridDim.x);
    const int tid = threadIdx.x;
    const int wv = tid >> 6, lane = tid & 63;
    const int lg = lane >> 4, lr = lane & 15;
    const int v0 = bid * 256 + wv * 64;
    if (v0 >= Nq) return;

    bool mw = false;
    {
        int q = v0 + lane;
        if (q < Nq) {
            int zq = q / YXq; int rr = q - zq * YXq; int yq = rr / Xq; int xq = rr - yq * Xq;
            int zz = 2 * zq + pz, yy = 2 * yq + py, xx = 2 * xq + px;
            mw = mask[(zz * Yo + yy) * Xo + xx] != 0;
        }
    }
    const bool anywork = (__ballot(mw) != 0ull);

    f32x4 acc[4][NT];
#pragma unroll
    for (int s = 0; s < 4; ++s)
#pragma unroll
        for (int nt = 0; nt < NT; ++nt) acc[s][nt] = (f32x4){0.f, 0.f, 0.f, 0.f};

    const uint4* gw = (const uint4*)wfrag;

    if (anywork) {
        int pA[4];
#pragma unroll
        for (int s = 0; s < 4; ++s) {
            int q = v0 + s * 16 + lr;
            if (q >= Nq) q = 0;
            int zq = q / YXq; int rr = q - zq * YXq; int yq = rr / Xq; int xq = rr - yq * Xq;
            pA[s] = (((zq + 1) * Ypi + (yq + 1)) * Xpi + (xq + 1)) * CIN + lg * 8;
        }
        const int nkz = 1 + pz, nky = 1 + py, nkx = 1 + px;
        for (int iz = 0; iz < nkz; ++iz) {
            const int kz = pz ? (iz ? 2 : 0) : 1;
            const int dz = (pz && !iz) ? 1 : 0;
            for (int iy = 0; iy < nky; ++iy) {
                const int ky = py ? (iy ? 2 : 0) : 1;
                const int dy = (py && !iy) ? 1 : 0;
                for (int ix = 0; ix < nkx; ++ix) {
                    const int kx = px ? (ix ? 2 : 0) : 1;
                    const int dx = (px && !ix) ? 1 : 0;
                    const int tap = kz * 9 + ky * 3 + kx;
                    const int toff = ((dz * Ypi + dy) * Xpi + dx) * CIN;
                    uint4 ub[NT][KT];
#pragma unroll
                    for (int nt = 0; nt < NT; ++nt)
#pragma unroll
                        for (int kt = 0; kt < KT; ++kt)
                            ub[nt][kt] = gw[((tap * NT + nt) * KT + kt) * 64 + lane];
                    uint4 ua[4][KT];
#pragma unroll
                    for (int s = 0; s < 4; ++s)
#pragma unroll
                        for (int kt = 0; kt < KT; ++kt)
                            ua[s][kt] = *(const uint4*)(in + pA[s] + toff + kt * 32);
#pragma unroll
                    for (int s = 0; s < 4; ++s)
#pragma unroll
                        for (int kt = 0; kt < KT; ++kt)
#pragma unroll
                            for (int nt = 0; nt < NT; ++nt)
                                acc[s][nt] = __builtin_amdgcn_mfma_f32_16x16x32_bf16(
                                    __builtin_bit_cast(s16x8, ua[s][kt]),
                                    __builtin_bit_cast(s16x8, ub[nt][kt]), acc[s][nt], 0, 0, 0);
                }
            }
        }
    }

#pragma unroll
    for (int s = 0; s < 4; ++s) {
        const int vb = v0 + s * 16 + lg * 4;
        int opd[4]; float mm[4]; bool ok[4];
#pragma unroll
        for (int r = 0; r < 4; ++r) {
            int q = vb + r;
            ok[r] = q < Nq;
            int qc = ok[r] ? q : 0;
            int zq = qc / YXq; int rr = qc - zq * YXq; int yq = rr / Xq; int xq = rr - yq * Xq;
            int zz = 2 * zq + pz, yy = 2 * yq + py, xx = 2 * xq + px;
            mm[r] = (ok[r] && mask[(zz * Yo + yy) * Xo + xx]) ? 1.f : 0.f;
            opd[r] = ((zz + 1) * Ypo + (yy + 1)) * Xpo + (xx + 1);
        }
#pragma unroll
        for (int nt = 0; nt < NT; ++nt) {
            int co = nt * 16 + lr;
            float sc = scale[co], sh = shift[co];
#pragma unroll
            for (int r = 0; r < 4; ++r) {
                if (!ok[r]) continue;
                float yv = fmaxf(fmaf(acc[s][nt][r], sc, sh), 0.f) * mm[r];
                out[(size_t)opd[r] * COUT + co] = __float2bfloat16(yv);
            }
        }
    }
}

__global__ __launch_bounds__(256, 4) void conv_l1_mfma_k(
    const bf16* __restrict__ in, const bf16* __restrict__ wfrag,
    const float* __restrict__ scale, const float* __restrict__ shift,
    const uint8_t* __restrict__ mask, bf16* __restrict__ out,
    int Zo, int Yo, int Xo, int Ypi, int Xpi, int Ypo, int Xpo) {
    const int No = Zo * Yo * Xo;
    const int bid = xcd_swz(blockIdx.x, gridDim.x);
    const int tid = threadIdx.x;
    const int wv = tid >> 6, lane = tid & 63;
    const int lg = lane >> 4, lr = lane & 15;
    const int v0 = bid * 256 + wv * 64;
    if (v0 >= No) return;

    int vm = v0 + lane;
    bool mw = (vm < No) && (mask[vm] != 0);
    const bool anywork = (__ballot(mw) != 0ull);

    f32x4 acc[4];
#pragma unroll
    for (int s = 0; s < 4; ++s) acc[s] = (f32x4){0.f, 0.f, 0.f, 0.f};

    if (anywork) {
        const uint4* gw = (const uint4*)wfrag;
        uint4 bu[4];
#pragma unroll
        for (int kb = 0; kb < 4; ++kb) bu[kb] = gw[kb * 64 + lane];

        int vtf[4][2];
#pragma unroll
        for (int kb = 0; kb < 4; ++kb)
#pragma unroll
            for (int u = 0; u < 2; ++u) {
                int tp = kb * 8 + lg * 2 + u;
                int kz = tp / 9, r9 = tp - kz * 9, ky = r9 / 3, kx = r9 - ky * 3;
                vtf[kb][u] = (tp < 27) ? (((kz - 1) * Ypi + (ky - 1)) * Xpi + (kx - 1)) : 0;
            }

        int pV[4];
#pragma unroll
        for (int s = 0; s < 4; ++s) {
            int vr = v0 + s * 16 + lr;
            if (vr >= No) vr = 0;
            int zz = vr / (Yo * Xo); int rr = vr - zz * (Yo * Xo);
            int yy = rr / Xo; int xx = rr - yy * Xo;
            pV[s] = ((zz + 1) * Ypi + (yy + 1)) * Xpi + (xx + 1);
        }

#pragma unroll
        for (int kb = 0; kb < 4; ++kb) {
#pragma unroll
            for (int s = 0; s < 4; ++s) {
                uint2 a0 = *(const uint2*)(in + (size_t)(pV[s] + vtf[kb][0]) * 4);
                uint2 a1 = *(const uint2*)(in + (size_t)(pV[s] + vtf[kb][1]) * 4);
                int4 ai; ai.x = a0.x; ai.y = a0.y; ai.z = a1.x; ai.w = a1.y;
                acc[s] = __builtin_amdgcn_mfma_f32_16x16x32_bf16(
                    __builtin_bit_cast(s16x8, ai),
                    __builtin_bit_cast(s16x8, bu[kb]), acc[s], 0, 0, 0);
            }
        }
    }

#pragma unroll
    for (int s = 0; s < 4; ++s) {
        const int vb = v0 + s * 16 + lg * 4;
        int co = lr;
        float sc = scale[co], sh = shift[co];
#pragma unroll
        for (int r = 0; r < 4; ++r) {
            int v = vb + r;
            if (v >= No) continue;
            float mm = mask[v] ? 1.f : 0.f;
            int zz = v / (Yo * Xo); int rr = v - zz * (Yo * Xo);
            int yy = rr / Xo; int xx = rr - yy * Xo;
            int opd = ((zz + 1) * Ypo + (yy + 1)) * Xpo + (xx + 1);
            float yv = fmaxf(fmaf(acc[s][r], sc, sh), 0.f) * mm;
            out[(size_t)opd * 16 + co] = __float2bfloat16(yv);
        }
    }
}

inline int nblk(int n) { return (n + 255) / 256; }
inline int cdiv(int a, int b) { return (a + b - 1) / b; }

}  // namespace

extern "C" void kernel_launch(void* const* d_in, const int* in_sizes, int n_in,
                              void* d_out, int out_size, void* d_ws, size_t ws_size,
                              hipStream_t stream) {
    const float* feats = (const float*)d_in[0];
    const int* coords = (const int*)d_in[1];
    const int NVOX = in_sizes[0] / 4;

    const float *w1 = (const float*)d_in[3], *s1 = (const float*)d_in[4], *b1 = (const float*)d_in[5];
    const float *w2a = (const float*)d_in[6], *s2a = (const float*)d_in[7], *b2a = (const float*)d_in[8];
    const float *w2b = (const float*)d_in[9], *s2b = (const float*)d_in[10], *b2b = (const float*)d_in[11];
    const float *w3a = (const float*)d_in[12], *s3a = (const float*)d_in[13], *b3a = (const float*)d_in[14];
    const float *w3b = (const float*)d_in[15], *s3b = (const float*)d_in[16], *b3b = (const float*)d_in[17];
    const float *w4a = (const float*)d_in[18], *s4a = (const float*)d_in[19], *b4a = (const float*)d_in[20];
    const float *w4b = (const float*)d_in[21], *s4b = (const float*)d_in[22], *b4b = (const float*)d_in[23];
    const float *w5a = (const float*)d_in[24], *s5a = (const float*)d_in[25], *b5a = (const float*)d_in[26];
    const float *w5b = (const float*)d_in[27], *s5b = (const float*)d_in[28], *b5b = (const float*)d_in[29];

    char* ws = (char*)d_ws;
    size_t off = 0;
    auto alloc = [&](size_t bytes) -> void* {
        void* p = ws + off;
        off = (off + bytes + 255) & ~(size_t)255;
        return p;
    };

    uint8_t* m0 = (uint8_t*)alloc(NV0);
    uint8_t* m1 = (uint8_t*)alloc(NV0);
    uint8_t* m2 = (uint8_t*)alloc(NV2);
    uint8_t* m3 = (uint8_t*)alloc(NV3);
    uint8_t* m4 = (uint8_t*)alloc(NV4);
    uint8_t* m5 = (uint8_t*)alloc(NV0);

    bf16* slot0 = (bf16*)alloc((size_t)NP0 * 32 * 2);
    bf16* slot1 = (bf16*)alloc((size_t)NP0 * 16 * 2);

    bf16* dense0 = slot0;  // 4ch  @P0
    bf16* x1     = slot1;  // 16ch @P0
    bf16* x2a    = slot0;  // 32ch @P2
    bf16* x2b    = slot1;  // 32ch @P2
    bf16* x3a    = slot0;  // 64ch @P3
    bf16* x3b    = slot1;  // 64ch @P3
    bf16* x4a    = slot0;  // 32ch @P4
    bf16* x4b    = slot1;  // 32ch @(23,130,130)
    bf16* x5a    = slot0;  // 32ch @P0

    bf16* wfL1 = (bf16*)alloc(4 * 64 * 8 * 2);
    bf16* wf2a = (bf16*)alloc((size_t)14 * 2 * 64 * 16);
    bf16* wf2b = (bf16*)alloc((size_t)27 * 2 * 1 * 64 * 16);
    bf16* wf3a = (bf16*)alloc((size_t)27 * 4 * 1 * 64 * 16);
    bf16* wf3b = (bf16*)alloc((size_t)27 * 4 * 2 * 64 * 16);
    bf16* wf4a = (bf16*)alloc((size_t)27 * 2 * 2 * 64 * 16);
    bf16* wf4b = (bf16*)alloc((size_t)27 * 2 * 1 * 64 * 16);
    bf16* wf5a = (bf16*)alloc((size_t)27 * 2 * 1 * 64 * 16);
    bf16* wf5b = (bf16*)alloc((size_t)27 * 2 * 1 * 64 * 16);
    alloc(20u << 20);  // slack for OOB halo reads of partial tiles

    if (off > ws_size) {
        sentinel_k<<<1, 256, 0, stream>>>((float*)d_out);
        return;
    }

    // stage 0
    hipMemsetAsync(dense0, 0, (size_t)NP0 * 4 * 2, stream);
    hipMemsetAsync(m0, 0, NV0, stream);
    repack_frag_l1_k<<<1, 256, 0, stream>>>(w1, wfL1);
    repack_frag_c16_k<<<nblk(14 * 2 * 64), 256, 0, stream>>>(w2a, wf2a);
    repack_frag_k<<<nblk(27 * 2 * 64), 256, 0, stream>>>(w2b, wf2b, 32, 32, 0);
    repack_frag_k<<<nblk(27 * 4 * 64), 256, 0, stream>>>(w3a, wf3a, 32, 64, 0);
    repack_frag_k<<<nblk(27 * 8 * 64), 256, 0, stream>>>(w3b, wf3b, 64, 64, 0);
    repack_frag_k<<<nblk(27 * 4 * 64), 256, 0, stream>>>(w4a, wf4a, 64, 32, 1);
    repack_frag_k<<<nblk(27 * 2 * 64), 256, 0, stream>>>(w4b, wf4b, 32, 32, 0);
    repack_frag_k<<<nblk(27 * 2 * 64), 256, 0, stream>>>(w5a, wf5a, 32, 32, 1);
    repack_frag_k<<<nblk(27 * 2 * 64), 256, 0, stream>>>(w5b, wf5b, 32, 32, 0);

    scatter_k<<<nblk(NVOX), 256, 0, stream>>>(feats, coords, dense0, m0, NVOX);

    // level 1
    dilate4_k<<<nblk(NV0 / 4), 256, 0, stream>>>(m0, m1, Z0, Y0, X0);
    halo_zero_k<16><<<nblk(NP0), 256, 0, stream>>>(x1, Z0, Y0, X0, ZP0, YP0, XP0);
    conv_l1_mfma_k<<<nblk(NV0), 256, 0, stream>>>(
        dense0, wfL1, s1, b1, m1, x1, Z0, Y0, X0, YP0, XP0, YP0, XP0);

    // level 2
    dilate_k<<<nblk(NV2), 256, 0, stream>>>(m1, m2, Z0, Y0, X0, Z2, Y2, X2, 2);
    halo_zero_k<32><<<nblk(NP2), 256, 0, stream>>>(x2a, Z2, Y2, X2, ZP2, YP2, XP2);
    conv_s2c16_k<<<nblk(NV2), 256, 0, stream>>>(
        x1, wf2a, s2a, b2a, m2, x2a, Z2, Y2, X2, YP0, XP0, YP2, XP2);
    halo_zero_k<32><<<nblk(NP2), 256, 0, stream>>>(x2b, Z2, Y2, X2, ZP2, YP2, XP2);
    {
        int nx = cdiv(X2, 32), ny = cdiv(Y2, 4), nz = cdiv(Z2, 4);
        conv_lds_k<false><<<nx * ny * nz, 512, 0, stream>>>(
            x2a, wf2b, s2b, b2b, m2, x2b, nullptr, Z2, Y2, X2, YP2, XP2, YP2, XP2, nx, ny);
    }

    // level 3 (both convs MFMA, 64-thread blocks for grid spread)
    dilate_k<<<nblk(NV3), 256, 0, stream>>>(m2, m3, Z2, Y2, X2, Z3, Y3, X3, 2);
    halo_zero_k<64><<<nblk(NP3), 256, 0, stream>>>(x3a, Z3, Y3, X3, ZP3, YP3, XP3);
    conv_mfma_k<32, 64, 2, 64, false><<<cdiv(NV3, 64), 64, 0, stream>>>(
        x2b, wf3a, s3a, b3a, m3, x3a, nullptr, Z3, Y3, X3, YP2, XP2, YP3, XP3);
    halo_zero_k<64><<<nblk(NP3), 256, 0, stream>>>(x3b, Z3, Y3, X3, ZP3, YP3, XP3);
    conv_mfma_k<64, 64, 1, 64, false><<<cdiv(NV3, 64), 64, 0, stream>>>(
        x3a, wf3b, s3b, b3b, m3, x3b, nullptr, Z3, Y3, X3, YP3, XP3, YP3, XP3);

    // level 4 (tconv up via parity octants)
    tdilate_k<<<nblk(NV4), 256, 0, stream>>>(m3, m4, Z3, Y3, X3, Z4, Y4, X4);
    halo_zero_k<32><<<nblk(NP4), 256, 0, stream>>>(x4a, Z4, Y4, X4, ZP4, YP4, XP4);
    {
        int maxNq = ((Z4 + 1) >> 1) * ((Y4 + 1) >> 1) * ((X4 + 1) >> 1);
        dim3 g(nblk(maxNq), 8);
        tconv_mfma_k<64, 32><<<g, 256, 0, stream>>>(
            x3b, wf4a, s4a, b4a, m4, x4a, Z4, Y4, X4, YP3, XP3, YP4, XP4);
    }
    halo_zero_k<32><<<nblk(NP2), 256, 0, stream>>>(x4b, Z4, Y4, X4, ZP2, YP2, XP2);
    {
        int nx = cdiv(X4, 32), ny = cdiv(Y4, 4), nz = cdiv(Z4, 4);
        conv_lds_k<false><<<nx * ny * nz, 512, 0, stream>>>(
            x4a, wf4b, s4b, b4b, m4, x4b, nullptr, Z4, Y4, X4, YP4, XP4, YP2, XP2, nx, ny);
    }

    // level 5 (tconv up, outpad (0,3,3))
    tdilate_k<<<nblk(NV0), 256, 0, stream>>>(m4, m5, Z4, Y4, X4, Z0, Y0, X0);
    halo_zero_k<32><<<nblk(NP0), 256, 0, stream>>>(x5a, Z0, Y0, X0, ZP0, YP0, XP0);
    {
        int maxNq = ((Z0 + 1) >> 1) * (Y0 >> 1) * (X0 >> 1);
        dim3 g(nblk(maxNq), 8);
        tconv_mfma_k<32, 32><<<g, 256, 0, stream>>>(
            x4b, wf5a, s5a, b5a, m5, x5a, Z0, Y0, X0, YP2, XP2, YP0, XP0);
    }
    {
        int nx = cdiv(X0, 32), ny = cdiv(Y0, 4), nz = cdiv(Z0, 4);
        conv_lds_k<true><<<nx * ny * nz, 512, 0, stream>>>(
            x5a, wf5b, s5b, b5b, m5, nullptr, (float*)d_out, Z0, Y0, X0, YP0, XP0, 0, 0, nx, ny);
    }
}